// Round 8
// baseline (627.436 us; speedup 1.0000x reference)
//
#include <hip/hip_runtime.h>
#include <math.h>

#define NN 100000
#define NE 1600000
#define NG 256
#define NPART 80
#define PS (NN / NPART)               // 1250 nodes per partition
#define CAP 22000                     // bucket capacity (mean 20000, +9 sigma)
#define EPB 2048                      // edges per bucket_k block
#define NBLK ((NE + EPB - 1) / EPB)   // 782
static constexpr float BN_EPS = 1e-5f;

// ---- fp16 helpers (HW RNE via v_cvt) ----
__device__ inline float h2f(unsigned short u) {
    _Float16 h; __builtin_memcpy(&h, &u, 2); return (float)h;
}
__device__ inline unsigned short f2h(float f) {
    _Float16 h = (_Float16)f; unsigned short u; __builtin_memcpy(&u, &h, 2); return u;
}
__device__ inline unsigned int pack2(float a, float b) {
    return (unsigned int)f2h(a) | ((unsigned int)f2h(b) << 16);
}

// ======= CSR stage 1: bucket edges by dst partition (LDS-ranked, ~62K atomics)
__global__ __launch_bounds__(256) void bucket_k(const int* __restrict__ src,
                                                const int* __restrict__ dst,
                                                int* __restrict__ bcur,
                                                int* __restrict__ bsrc,
                                                int* __restrict__ bdst) {
    __shared__ int cnt[NPART];
    __shared__ int base[NPART];
    int t = threadIdx.x;
    for (int i = t; i < NPART; i += 256) cnt[i] = 0;
    __syncthreads();
    int eb = blockIdx.x * EPB + t * 8;     // NE - e0 is a multiple of 8 -> all-or-nothing
    bool act = eb < NE;
    int myd[8], mys[8], myp[8], myr[8];
    if (act) {
        int4 d0 = *reinterpret_cast<const int4*>(dst + eb);
        int4 d1 = *reinterpret_cast<const int4*>(dst + eb + 4);
        int4 s0 = *reinterpret_cast<const int4*>(src + eb);
        int4 s1 = *reinterpret_cast<const int4*>(src + eb + 4);
        myd[0]=d0.x; myd[1]=d0.y; myd[2]=d0.z; myd[3]=d0.w;
        myd[4]=d1.x; myd[5]=d1.y; myd[6]=d1.z; myd[7]=d1.w;
        mys[0]=s0.x; mys[1]=s0.y; mys[2]=s0.z; mys[3]=s0.w;
        mys[4]=s1.x; mys[5]=s1.y; mys[6]=s1.z; mys[7]=s1.w;
        #pragma unroll
        for (int i = 0; i < 8; i++) {
            myp[i] = myd[i] / PS;
            myr[i] = atomicAdd(&cnt[myp[i]], 1);
        }
    }
    __syncthreads();
    for (int i = t; i < NPART; i += 256)
        base[i] = cnt[i] ? atomicAdd(&bcur[i], cnt[i]) : 0;
    __syncthreads();
    if (act) {
        #pragma unroll
        for (int i = 0; i < 8; i++) {
            int pos = myp[i] * CAP + base[myp[i]] + myr[i];
            bsrc[pos] = mys[i];
            bdst[pos] = myd[i];
        }
    }
}

// ======= CSR stage 2: per-partition hist + scan + place (LDS cursors only) ===
__global__ __launch_bounds__(256) void build_k(const int* __restrict__ bcur,
                                               const int* __restrict__ bsrc,
                                               const int* __restrict__ bdst,
                                               int* __restrict__ rowptr,
                                               int* __restrict__ csr) {
    __shared__ int hist[PS];      // 1250: histogram, then cursor
    __shared__ int allc[NPART];
    __shared__ int psum[256];
    int p = blockIdx.x, t = threadIdx.x;
    int lo = p * PS;
    if (t < NPART) allc[t] = bcur[t];
    for (int i = t; i < PS; i += 256) hist[i] = 0;
    __syncthreads();
    int base = 0;
    for (int q = 0; q < p; q++) base += allc[q];
    int cnt = allc[p];
    const int* bd = bdst + p * CAP;
    const int* bs = bsrc + p * CAP;
    // pass A: histogram (int4 main loop)
    int n4 = cnt >> 2;
    const int4* bd4 = reinterpret_cast<const int4*>(bd);
    for (int i = t; i < n4; i += 256) {
        int4 v = bd4[i];
        atomicAdd(&hist[v.x - lo], 1);
        atomicAdd(&hist[v.y - lo], 1);
        atomicAdd(&hist[v.z - lo], 1);
        atomicAdd(&hist[v.w - lo], 1);
    }
    for (int i = 4 * n4 + t; i < cnt; i += 256) atomicAdd(&hist[bd[i] - lo], 1);
    __syncthreads();
    // scan: thread t owns hist[5t .. 5t+5)
    int j0 = t * 5;
    int tsum = 0;
    if (j0 < PS) {
        #pragma unroll
        for (int j = 0; j < 5; j++) tsum += hist[j0 + j];
    }
    psum[t] = tsum;
    __syncthreads();
    for (int off = 1; off < 256; off <<= 1) {
        int v = (t >= off) ? psum[t - off] : 0;
        __syncthreads();
        psum[t] += v;
        __syncthreads();
    }
    int texcl = psum[t] - tsum;
    if (j0 < PS) {
        int run = base + texcl;
        #pragma unroll
        for (int j = 0; j < 5; j++) {
            int h = hist[j0 + j];
            hist[j0 + j] = run;          // cursor start
            rowptr[lo + j0 + j] = run;
            run += h;
        }
    }
    if (p == NPART - 1 && t == 0) rowptr[NN] = base + cnt;
    __syncthreads();
    // pass B: place (writes confined to 80KB csr window -> L2-assembled)
    const int4* bs4 = reinterpret_cast<const int4*>(bs);
    for (int i = t; i < n4; i += 256) {
        int4 d = bd4[i];
        int4 s = bs4[i];
        csr[atomicAdd(&hist[d.x - lo], 1)] = s.x;
        csr[atomicAdd(&hist[d.y - lo], 1)] = s.y;
        csr[atomicAdd(&hist[d.z - lo], 1)] = s.z;
        csr[atomicAdd(&hist[d.w - lo], 1)] = s.w;
    }
    for (int i = 4 * n4 + t; i < cnt; i += 256)
        csr[atomicAdd(&hist[bd[i] - lo], 1)] = bs[i];
}

// ============== layer 1: gather(d=2) + MLP 2->32->32 + stats0 ==============
__global__ __launch_bounds__(64) void gmlp1_k(
        const float* __restrict__ x,
        const int* __restrict__ rowptr, const int* __restrict__ csr,
        const float* __restrict__ w_in, const float* __restrict__ b_in,
        const float* __restrict__ w_out, const float* __restrict__ b_out,
        unsigned short* __restrict__ zout, float* __restrict__ stats) {
    __shared__ float lwi[64], lbi[32], lwo[1024], lbo[32];
    __shared__ float zl[64][33];
    int t = threadIdx.x;
    lwi[t] = w_in[t];
    if (t < 32) { lbi[t] = b_in[t]; lbo[t] = b_out[t]; }
    for (int i = t; i < 1024; i += 64) lwo[i] = w_out[i];
    __syncthreads();
    int node = blockIdx.x * 64 + t;
    if (node < NN) {
        float2 self = *reinterpret_cast<const float2*>(x + 2 * (size_t)node);
        float h0 = self.x, h1 = self.y;
        float g0 = 0.f, g1 = 0.f;
        int rs = rowptr[node], re = rowptr[node + 1];
        int k = rs;
        for (; k + 4 <= re; k += 4) {
            int s0 = csr[k], s1 = csr[k+1], s2 = csr[k+2], s3 = csr[k+3];
            float2 v0 = *reinterpret_cast<const float2*>(x + 2 * (size_t)s0);
            float2 v1 = *reinterpret_cast<const float2*>(x + 2 * (size_t)s1);
            float2 v2 = *reinterpret_cast<const float2*>(x + 2 * (size_t)s2);
            float2 v3 = *reinterpret_cast<const float2*>(x + 2 * (size_t)s3);
            h0 += v0.x + v2.x; h1 += v0.y + v2.y;
            g0 += v1.x + v3.x; g1 += v1.y + v3.y;
        }
        for (; k < re; k++) {
            int s = csr[k];
            float2 v = *reinterpret_cast<const float2*>(x + 2 * (size_t)s);
            h0 += v.x; h1 += v.y;
        }
        h0 += g0; h1 += g1;
        float y[32];
        #pragma unroll
        for (int kk = 0; kk < 32; kk++) {
            float a = lbi[kk] + h0 * lwi[kk] + h1 * lwi[32 + kk];
            y[kk] = a > 0.f ? a : 0.f;
        }
        float z[32];
        #pragma unroll 4
        for (int kk = 0; kk < 32; kk++) {
            float a = lbo[kk];
            #pragma unroll
            for (int c = 0; c < 32; c++) a += y[c] * lwo[c * 32 + kk];
            z[kk] = a > 0.f ? a : 0.f;
        }
        uint4* zo = reinterpret_cast<uint4*>(zout + (size_t)node * 32);
        #pragma unroll
        for (int kk = 0; kk < 4; kk++) {
            uint4 w;
            w.x = pack2(z[8*kk+0], z[8*kk+1]);
            w.y = pack2(z[8*kk+2], z[8*kk+3]);
            w.z = pack2(z[8*kk+4], z[8*kk+5]);
            w.w = pack2(z[8*kk+6], z[8*kk+7]);
            zo[kk] = w;
        }
        #pragma unroll
        for (int kk = 0; kk < 32; kk++) zl[t][kk] = z[kk];
    } else {
        for (int kk = 0; kk < 32; kk++) zl[t][kk] = 0.f;
    }
    __syncthreads();
    if (t < 32) {
        float s = 0.f, sq = 0.f;
        for (int n = 0; n < 64; n++) { float v = zl[n][t]; s += v; sq += v * v; }
        atomicAdd(&stats[t], s);
        atomicAdd(&stats[32 + t], sq);
    }
}

// ======= heavy layer: in-block BN + gather(fp16, x4 unroll) + MLP + stats ====
__global__ __launch_bounds__(256) void gmlp32_k(
        const unsigned short* __restrict__ z,
        const float* __restrict__ statsIn,
        const float* __restrict__ gamma, const float* __restrict__ beta,
        const int* __restrict__ rowptr, const int* __restrict__ csr,
        const float* __restrict__ w_in, const float* __restrict__ b_in,
        const float* __restrict__ w_out, const float* __restrict__ b_out,
        unsigned short* __restrict__ zout, float* __restrict__ statsOut) {
    __shared__ float lwi[1024], lwo[1024], lbi[32], lbo[32], lsc[64];
    __shared__ float zin[32][33];
    __shared__ float yl[32][33];
    __shared__ float part[256][8];
    int t = threadIdx.x;
    int n = t >> 3, q = t & 7, c0 = q * 4;
    for (int i = t; i < 1024; i += 256) { lwi[i] = w_in[i]; lwo[i] = w_out[i]; }
    if (t < 32) {
        lbi[t] = b_in[t]; lbo[t] = b_out[t];
        float mean = statsIn[t] * (1.f / NN);
        float var  = statsIn[32 + t] * (1.f / NN) - mean * mean;
        float scale = gamma[t] * rsqrtf(var + BN_EPS);
        lsc[t] = scale;
        lsc[32 + t] = beta[t] - mean * scale;
    }
    __syncthreads();
    int node = blockIdx.x * 32 + n;
    int rs = rowptr[node], re = rowptr[node + 1];
    ushort4 sv = *reinterpret_cast<const ushort4*>(z + (size_t)node * 32 + c0);
    float a0 = h2f(sv.x), a1 = h2f(sv.y), a2 = h2f(sv.z), a3 = h2f(sv.w);
    float b0 = 0.f, b1 = 0.f, b2 = 0.f, b3 = 0.f;
    int k = rs;
    for (; k + 4 <= re; k += 4) {
        int s0 = csr[k], s1 = csr[k+1], s2 = csr[k+2], s3 = csr[k+3];
        ushort4 v0 = *reinterpret_cast<const ushort4*>(z + (size_t)s0 * 32 + c0);
        ushort4 v1 = *reinterpret_cast<const ushort4*>(z + (size_t)s1 * 32 + c0);
        ushort4 v2 = *reinterpret_cast<const ushort4*>(z + (size_t)s2 * 32 + c0);
        ushort4 v3 = *reinterpret_cast<const ushort4*>(z + (size_t)s3 * 32 + c0);
        a0 += h2f(v0.x) + h2f(v2.x); a1 += h2f(v0.y) + h2f(v2.y);
        a2 += h2f(v0.z) + h2f(v2.z); a3 += h2f(v0.w) + h2f(v2.w);
        b0 += h2f(v1.x) + h2f(v3.x); b1 += h2f(v1.y) + h2f(v3.y);
        b2 += h2f(v1.z) + h2f(v3.z); b3 += h2f(v1.w) + h2f(v3.w);
    }
    for (; k < re; k++) {
        int s = csr[k];
        ushort4 v = *reinterpret_cast<const ushort4*>(z + (size_t)s * 32 + c0);
        a0 += h2f(v.x); a1 += h2f(v.y); a2 += h2f(v.z); a3 += h2f(v.w);
    }
    a0 += b0; a1 += b1; a2 += b2; a3 += b3;
    float cnt = (float)(re - rs + 1);
    zin[n][c0+0] = a0 * lsc[c0+0] + cnt * lsc[32+c0+0];
    zin[n][c0+1] = a1 * lsc[c0+1] + cnt * lsc[32+c0+1];
    zin[n][c0+2] = a2 * lsc[c0+2] + cnt * lsc[32+c0+2];
    zin[n][c0+3] = a3 * lsc[c0+3] + cnt * lsc[32+c0+3];
    __syncthreads();
    float acc0 = lbi[c0+0], acc1 = lbi[c0+1], acc2 = lbi[c0+2], acc3 = lbi[c0+3];
    #pragma unroll
    for (int c = 0; c < 32; c++) {
        float zv = zin[n][c];
        acc0 += zv * lwi[c*32 + c0+0];
        acc1 += zv * lwi[c*32 + c0+1];
        acc2 += zv * lwi[c*32 + c0+2];
        acc3 += zv * lwi[c*32 + c0+3];
    }
    yl[n][c0+0] = acc0 > 0.f ? acc0 : 0.f;
    yl[n][c0+1] = acc1 > 0.f ? acc1 : 0.f;
    yl[n][c0+2] = acc2 > 0.f ? acc2 : 0.f;
    yl[n][c0+3] = acc3 > 0.f ? acc3 : 0.f;
    __syncthreads();
    float o0 = lbo[c0+0], o1 = lbo[c0+1], o2 = lbo[c0+2], o3 = lbo[c0+3];
    #pragma unroll
    for (int c = 0; c < 32; c++) {
        float yv = yl[n][c];
        o0 += yv * lwo[c*32 + c0+0];
        o1 += yv * lwo[c*32 + c0+1];
        o2 += yv * lwo[c*32 + c0+2];
        o3 += yv * lwo[c*32 + c0+3];
    }
    o0 = o0 > 0.f ? o0 : 0.f;
    o1 = o1 > 0.f ? o1 : 0.f;
    o2 = o2 > 0.f ? o2 : 0.f;
    o3 = o3 > 0.f ? o3 : 0.f;
    uint2 wout;
    wout.x = pack2(o0, o1);
    wout.y = pack2(o2, o3);
    *reinterpret_cast<uint2*>(zout + (size_t)node * 32 + c0) = wout;
    part[t][0] = o0; part[t][1] = o1; part[t][2] = o2; part[t][3] = o3;
    part[t][4] = o0*o0; part[t][5] = o1*o1; part[t][6] = o2*o2; part[t][7] = o3*o3;
    __syncthreads();
    if (t < 32) {
        int ch = t, qq = ch >> 2, j = ch & 3;
        float s = 0.f, sq2 = 0.f;
        for (int nn = 0; nn < 32; nn++) {
            s   += part[nn*8 + qq][j];
            sq2 += part[nn*8 + qq][4 + j];
        }
        atomicAdd(&statsOut[ch], s);
        atomicAdd(&statsOut[32 + ch], sq2);
    }
}

// ====== pool: batch is SORTED -> one block per graph, binary search ======
__global__ __launch_bounds__(256) void pool_seg_k(
        const unsigned short* __restrict__ z,
        const float* __restrict__ statsIn,
        const float* __restrict__ gamma, const float* __restrict__ beta,
        const int* __restrict__ batch, float* __restrict__ g) {
    __shared__ float lsc[64];
    __shared__ float part[32][33];
    int t = threadIdx.x, slot = t >> 3, q = t & 7, c0 = q * 4;
    int gr = blockIdx.x;
    if (t < 32) {
        float mean = statsIn[t] * (1.f / NN);
        float var  = statsIn[32 + t] * (1.f / NN) - mean * mean;
        float scale = gamma[t] * rsqrtf(var + BN_EPS);
        lsc[t] = scale;
        lsc[32 + t] = beta[t] - mean * scale;
    }
    int lo = 0, hi = NN;
    while (lo < hi) { int mid = (lo + hi) >> 1; if (batch[mid] < gr) lo = mid + 1; else hi = mid; }
    int start = lo;
    hi = NN;
    while (lo < hi) { int mid = (lo + hi) >> 1; if (batch[mid] < gr + 1) lo = mid + 1; else hi = mid; }
    int end = lo;
    float a0 = 0.f, a1 = 0.f, a2 = 0.f, a3 = 0.f;
    for (int i = start + slot; i < end; i += 32) {
        ushort4 v = *reinterpret_cast<const ushort4*>(z + (size_t)i * 32 + c0);
        a0 += h2f(v.x); a1 += h2f(v.y); a2 += h2f(v.z); a3 += h2f(v.w);
    }
    part[slot][c0+0] = a0; part[slot][c0+1] = a1;
    part[slot][c0+2] = a2; part[slot][c0+3] = a3;
    __syncthreads();
    if (t < 32) {
        float s = 0.f;
        for (int sl = 0; sl < 32; sl++) s += part[sl][t];
        float cnt = (float)(end - start);
        g[(size_t)gr * 32 + t] = s * lsc[t] + cnt * lsc[32 + t];
    }
}

// ---------------- head: fc1 -> relu -> fc2 -> log_softmax ----------------
__global__ __launch_bounds__(256) void head_k(
        const float* __restrict__ g,
        const float* __restrict__ fc1w, const float* __restrict__ fc1b,
        const float* __restrict__ fc2w, const float* __restrict__ fc2b,
        float* __restrict__ out) {
    __shared__ float lw1[1024], lb1[32], lw2[64], lb2[2];
    int t = threadIdx.x;
    for (int i = t; i < 1024; i += 256) lw1[i] = fc1w[i];
    if (t < 32) lb1[t] = fc1b[t];
    if (t < 64) lw2[t] = fc2w[t];
    if (t < 2) lb2[t] = fc2b[t];
    __syncthreads();
    float gv[32];
    #pragma unroll
    for (int c = 0; c < 32; c++) gv[c] = g[(size_t)t * 32 + c];
    float o0 = lb2[0], o1 = lb2[1];
    #pragma unroll 4
    for (int k = 0; k < 32; k++) {
        float a = lb1[k];
        #pragma unroll
        for (int c = 0; c < 32; c++) a += gv[c] * lw1[c * 32 + k];
        a = a > 0.f ? a : 0.f;
        o0 += a * lw2[k * 2 + 0];
        o1 += a * lw2[k * 2 + 1];
    }
    float m = fmaxf(o0, o1);
    float lse = m + logf(expf(o0 - m) + expf(o1 - m));
    out[t * 2 + 0] = o0 - lse;
    out[t * 2 + 1] = o1 - lse;
}

extern "C" void kernel_launch(void* const* d_in, const int* in_sizes, int n_in,
                              void* d_out, int out_size, void* d_ws, size_t ws_size,
                              hipStream_t stream) {
    const float* x      = (const float*)d_in[0];
    const int*   ei     = (const int*)d_in[1];
    const int*   src    = ei;
    const int*   dst    = ei + NE;
    const int*   batch  = (const int*)d_in[2];
    const float* w1_in  = (const float*)d_in[3];
    const float* b1_in  = (const float*)d_in[4];
    const float* w1_out = (const float*)d_in[5];
    const float* b1_out = (const float*)d_in[6];
    const float* ws_in  = (const float*)d_in[7];
    const float* bs_in  = (const float*)d_in[8];
    const float* ws_out = (const float*)d_in[9];
    const float* bs_out = (const float*)d_in[10];
    const float* gamma  = (const float*)d_in[11];
    const float* beta   = (const float*)d_in[12];
    const float* fc1w   = (const float*)d_in[13];
    const float* fc1b   = (const float*)d_in[14];
    const float* fc2w   = (const float*)d_in[15];
    const float* fc2b   = (const float*)d_in[16];
    float* out = (float*)d_out;

    // ---- workspace layout (16B alignment maintained for int4 paths) ----
    unsigned short* bufA = (unsigned short*)d_ws;        // NN*32 fp16
    unsigned short* bufB = bufA + (size_t)NN * 32;       // NN*32 fp16
    float* stats  = (float*)(bufB + (size_t)NN * 32);    // 5*64 (zeroed)
    int*   bcur   = (int*)(stats + 5 * 64);              // NPART (zeroed, adjacent)
    float* g      = (float*)(bcur + NPART);              // NG*32
    int*   rowptr = (int*)(g + (size_t)NG * 32);         // NN+4 (padded for alignment)
    int*   csr    = rowptr + NN + 4;                     // NE
    int*   bsrc   = csr + NE;                            // NPART*CAP
    int*   bdst   = bsrc + (size_t)NPART * CAP;          // NPART*CAP

    // ---- zero stats + bucket cursors in one memset ----
    hipMemsetAsync(stats, 0, (size_t)(5 * 64 + NPART) * sizeof(int), stream);

    // ---- CSR build: bucket (1 pass, ~62K atomics) + per-partition build ----
    bucket_k<<<NBLK, 256, 0, stream>>>(src, dst, bcur, bsrc, bdst);
    build_k<<<NPART, 256, 0, stream>>>(bcur, bsrc, bdst, rowptr, csr);

    // ---- layer 1 (input dim 2) -> stats[0] ----
    gmlp1_k<<<(NN + 63) / 64, 64, 0, stream>>>(x, rowptr, csr,
                                               w1_in, b1_in, w1_out, b1_out, bufA, stats);

    // ---- layers 2..5 (input dim 32); BN(j) recomputed in-block ----
    const unsigned short* cur = bufA;
    unsigned short* nxt = bufB;
    for (int j = 0; j < 4; j++) {
        gmlp32_k<<<NN / 32, 256, 0, stream>>>(cur, stats + j * 64,
                                              gamma + j * 32, beta + j * 32,
                                              rowptr, csr,
                                              ws_in + j * 1024, bs_in + j * 32,
                                              ws_out + j * 1024, bs_out + j * 32,
                                              nxt, stats + (j + 1) * 64);
        unsigned short* tmp = (unsigned short*)cur; cur = nxt; nxt = tmp;
    }

    // ---- pool (BN(4) in-block) + head ----
    pool_seg_k<<<NG, 256, 0, stream>>>(cur, stats + 4 * 64,
                                       gamma + 4 * 32, beta + 4 * 32, batch, g);
    head_k<<<1, 256, 0, stream>>>(g, fc1w, fc1b, fc2w, fc2b, out);
}

// Round 9
// 576.857 us; speedup vs baseline: 1.0877x; 1.0877x over previous
//
#include <hip/hip_runtime.h>
#include <math.h>

#define NN 100000
#define NE 1600000
#define NG 256
#define NPART 200
#define PS 500                        // nodes per partition (9 bits)
#define CAP 9000                      // bucket capacity (mean 8000, +11 sigma)
#define EPB 2048                      // edges per bucket_k block
#define NBLK ((NE + EPB - 1) / EPB)   // 782
#define DEGB 64                       // degree bins for counting sort
static constexpr float BN_EPS = 1e-5f;

// ---- fp16 helpers (HW RNE via v_cvt) ----
__device__ inline float h2f(unsigned short u) {
    _Float16 h; __builtin_memcpy(&h, &u, 2); return (float)h;
}
__device__ inline unsigned short f2h(float f) {
    _Float16 h = (_Float16)f; unsigned short u; __builtin_memcpy(&u, &h, 2); return u;
}
__device__ inline unsigned int pack2(float a, float b) {
    return (unsigned int)f2h(a) | ((unsigned int)f2h(b) << 16);
}

// ======= CSR stage 1: bucket edges by dst partition; packed u32 payload ======
// pk = (src << 9) | (dst - p*PS);  src < 2^17, dst-lo < 512
__global__ __launch_bounds__(256) void bucket_k(const int* __restrict__ src,
                                                const int* __restrict__ dst,
                                                int* __restrict__ bcur,
                                                unsigned int* __restrict__ bpk) {
    __shared__ int cnt[NPART];
    __shared__ int base[NPART];
    int t = threadIdx.x;
    for (int i = t; i < NPART; i += 256) cnt[i] = 0;
    __syncthreads();
    int eb = blockIdx.x * EPB + t * 8;   // all-or-nothing (tail is 64x8)
    bool act = eb < NE;
    int myp[8], myr[8];
    unsigned int pk[8];
    if (act) {
        int4 d0 = *reinterpret_cast<const int4*>(dst + eb);
        int4 d1 = *reinterpret_cast<const int4*>(dst + eb + 4);
        int4 s0 = *reinterpret_cast<const int4*>(src + eb);
        int4 s1 = *reinterpret_cast<const int4*>(src + eb + 4);
        int dd[8] = {d0.x,d0.y,d0.z,d0.w,d1.x,d1.y,d1.z,d1.w};
        int ss[8] = {s0.x,s0.y,s0.z,s0.w,s1.x,s1.y,s1.z,s1.w};
        #pragma unroll
        for (int i = 0; i < 8; i++) {
            int p = dd[i] / PS;
            myp[i] = p;
            pk[i] = ((unsigned int)ss[i] << 9) | (unsigned int)(dd[i] - p * PS);
            myr[i] = atomicAdd(&cnt[p], 1);
        }
    }
    __syncthreads();
    for (int i = t; i < NPART; i += 256)
        base[i] = cnt[i] ? atomicAdd(&bcur[i], cnt[i]) : 0;
    __syncthreads();
    if (act) {
        #pragma unroll
        for (int i = 0; i < 8; i++)
            bpk[myp[i] * CAP + base[myp[i]] + myr[i]] = pk[i];
    }
}

// ==== CSR stage 2: per-partition hist + scan + deg-sort perm + place =========
__global__ __launch_bounds__(256) void build_k(const int* __restrict__ bcur,
                                               const unsigned int* __restrict__ bpk,
                                               int* __restrict__ rowptr,
                                               int* __restrict__ csr,
                                               int* __restrict__ perm) {
    __shared__ int hist[PS];          // histogram -> cursor
    __shared__ int allc[NPART];
    __shared__ int psum[256];
    __shared__ int bc[DEGB];
    int p = blockIdx.x, t = threadIdx.x;
    int lo = p * PS;
    if (t < NPART) allc[t] = bcur[t];
    for (int i = t; i < PS; i += 256) hist[i] = 0;
    if (t < DEGB) bc[t] = 0;
    __syncthreads();
    int base = 0;
    for (int q = 0; q < p; q++) base += allc[q];
    int cnt = allc[p];
    const unsigned int* bp = bpk + p * CAP;
    const uint4* bp4 = reinterpret_cast<const uint4*>(bp);
    int n4 = cnt >> 2;
    // pass A: degree histogram
    for (int i = t; i < n4; i += 256) {
        uint4 v = bp4[i];
        atomicAdd(&hist[v.x & 511u], 1);
        atomicAdd(&hist[v.y & 511u], 1);
        atomicAdd(&hist[v.z & 511u], 1);
        atomicAdd(&hist[v.w & 511u], 1);
    }
    for (int i = 4 * n4 + t; i < cnt; i += 256) atomicAdd(&hist[bp[i] & 511u], 1);
    __syncthreads();
    // thread t owns nodes j0, j0+1
    int j0 = t * 2;
    int d0v = 0, d1v = 0, tsum = 0;
    if (j0 < PS) {
        d0v = hist[j0]; d1v = hist[j0 + 1];
        tsum = d0v + d1v;
        atomicAdd(&bc[d0v < DEGB ? d0v : DEGB - 1], 1);
        atomicAdd(&bc[d1v < DEGB ? d1v : DEGB - 1], 1);
    }
    psum[t] = tsum;
    __syncthreads();
    for (int off = 1; off < 256; off <<= 1) {
        int v = (t >= off) ? psum[t - off] : 0;
        __syncthreads();
        psum[t] += v;
        __syncthreads();
    }
    int texcl = psum[t] - tsum;
    if (j0 < PS) {
        int run = base + texcl;
        hist[j0] = run; rowptr[lo + j0] = run; run += d0v;
        hist[j0 + 1] = run; rowptr[lo + j0 + 1] = run; run += d1v;
    }
    if (p == NPART - 1 && t == 0) rowptr[NN] = base + cnt;
    __syncthreads();
    // degree-bin exclusive scan (serial, 64 adds)
    if (t == 0) {
        int run = 0;
        #pragma unroll
        for (int b = 0; b < DEGB; b++) { int c = bc[b]; bc[b] = run; run += c; }
    }
    __syncthreads();
    // place perm (partition-contiguous, sorted by degree)
    if (j0 < PS) {
        int r0 = atomicAdd(&bc[d0v < DEGB ? d0v : DEGB - 1], 1);
        perm[lo + r0] = lo + j0;
        int r1 = atomicAdd(&bc[d1v < DEGB ? d1v : DEGB - 1], 1);
        perm[lo + r1] = lo + j0 + 1;
    }
    __syncthreads();
    // pass B: place csr (writes confined to 32KB window -> L2-assembled)
    for (int i = t; i < n4; i += 256) {
        uint4 v = bp4[i];
        csr[atomicAdd(&hist[v.x & 511u], 1)] = v.x >> 9;
        csr[atomicAdd(&hist[v.y & 511u], 1)] = v.y >> 9;
        csr[atomicAdd(&hist[v.z & 511u], 1)] = v.z >> 9;
        csr[atomicAdd(&hist[v.w & 511u], 1)] = v.w >> 9;
    }
    for (int i = 4 * n4 + t; i < cnt; i += 256)
        csr[atomicAdd(&hist[bp[i] & 511u], 1)] = bp[i] >> 9;
}

// ============== layer 1: gather(d=2) + MLP 2->32->32 + stats0 ==============
__global__ __launch_bounds__(64) void gmlp1_k(
        const float* __restrict__ x, const int* __restrict__ perm,
        const int* __restrict__ rowptr, const int* __restrict__ csr,
        const float* __restrict__ w_in, const float* __restrict__ b_in,
        const float* __restrict__ w_out, const float* __restrict__ b_out,
        unsigned short* __restrict__ zout, float* __restrict__ stats) {
    __shared__ float lwi[64], lbi[32], lwo[1024], lbo[32];
    __shared__ float zl[64][33];
    int t = threadIdx.x;
    lwi[t] = w_in[t];
    if (t < 32) { lbi[t] = b_in[t]; lbo[t] = b_out[t]; }
    for (int i = t; i < 1024; i += 64) lwo[i] = w_out[i];
    __syncthreads();
    int gid = blockIdx.x * 64 + t;
    if (gid < NN) {
        int node = perm[gid];
        float2 self = *reinterpret_cast<const float2*>(x + 2 * (size_t)node);
        float h0 = self.x, h1 = self.y;
        float g0 = 0.f, g1 = 0.f;
        int rs = rowptr[node], re = rowptr[node + 1];
        int k = rs;
        for (; k + 4 <= re; k += 4) {
            int s0 = csr[k], s1 = csr[k+1], s2 = csr[k+2], s3 = csr[k+3];
            float2 v0 = *reinterpret_cast<const float2*>(x + 2 * (size_t)s0);
            float2 v1 = *reinterpret_cast<const float2*>(x + 2 * (size_t)s1);
            float2 v2 = *reinterpret_cast<const float2*>(x + 2 * (size_t)s2);
            float2 v3 = *reinterpret_cast<const float2*>(x + 2 * (size_t)s3);
            h0 += v0.x + v2.x; h1 += v0.y + v2.y;
            g0 += v1.x + v3.x; g1 += v1.y + v3.y;
        }
        for (; k < re; k++) {
            int s = csr[k];
            float2 v = *reinterpret_cast<const float2*>(x + 2 * (size_t)s);
            h0 += v.x; h1 += v.y;
        }
        h0 += g0; h1 += g1;
        float y[32];
        #pragma unroll
        for (int kk = 0; kk < 32; kk++) {
            float a = lbi[kk] + h0 * lwi[kk] + h1 * lwi[32 + kk];
            y[kk] = a > 0.f ? a : 0.f;
        }
        float z[32];
        #pragma unroll 4
        for (int kk = 0; kk < 32; kk++) {
            float a = lbo[kk];
            #pragma unroll
            for (int c = 0; c < 32; c++) a += y[c] * lwo[c * 32 + kk];
            z[kk] = a > 0.f ? a : 0.f;
        }
        uint4* zo = reinterpret_cast<uint4*>(zout + (size_t)node * 32);
        #pragma unroll
        for (int kk = 0; kk < 4; kk++) {
            uint4 w;
            w.x = pack2(z[8*kk+0], z[8*kk+1]);
            w.y = pack2(z[8*kk+2], z[8*kk+3]);
            w.z = pack2(z[8*kk+4], z[8*kk+5]);
            w.w = pack2(z[8*kk+6], z[8*kk+7]);
            zo[kk] = w;
        }
        #pragma unroll
        for (int kk = 0; kk < 32; kk++) zl[t][kk] = z[kk];
    } else {
        for (int kk = 0; kk < 32; kk++) zl[t][kk] = 0.f;
    }
    __syncthreads();
    if (t < 32) {
        float s = 0.f, sq = 0.f;
        for (int n = 0; n < 64; n++) { float v = zl[n][t]; s += v; sq += v * v; }
        atomicAdd(&stats[t], s);
        atomicAdd(&stats[32 + t], sq);
    }
}

// ======= heavy layer: perm + in-block BN + gather(fp16 x4) + MLP + stats =====
// 256 threads = 32 nodes x 8 lanes; lane owns 4 channels.
__global__ __launch_bounds__(256) void gmlp32_k(
        const unsigned short* __restrict__ z, const int* __restrict__ perm,
        const float* __restrict__ statsIn,
        const float* __restrict__ gamma, const float* __restrict__ beta,
        const int* __restrict__ rowptr, const int* __restrict__ csr,
        const float* __restrict__ w_in, const float* __restrict__ b_in,
        const float* __restrict__ w_out, const float* __restrict__ b_out,
        unsigned short* __restrict__ zout, float* __restrict__ statsOut) {
    __shared__ float lwi[1024], lwo[1024], lbi[32], lbo[32], lsc[64];
    __shared__ float zin[32][33];
    __shared__ float yl[32][33];
    int t = threadIdx.x;
    int n = t >> 3, q = t & 7, c0 = q * 4;
    for (int i = t; i < 1024; i += 256) { lwi[i] = w_in[i]; lwo[i] = w_out[i]; }
    if (t < 32) {
        lbi[t] = b_in[t]; lbo[t] = b_out[t];
        float mean = statsIn[t] * (1.f / NN);
        float var  = statsIn[32 + t] * (1.f / NN) - mean * mean;
        float scale = gamma[t] * rsqrtf(var + BN_EPS);
        lsc[t] = scale;
        lsc[32 + t] = beta[t] - mean * scale;
    }
    __syncthreads();
    int node = perm[blockIdx.x * 32 + n];
    int rs = rowptr[node], re = rowptr[node + 1];
    ushort4 sv = *reinterpret_cast<const ushort4*>(z + (size_t)node * 32 + c0);
    float a0 = h2f(sv.x), a1 = h2f(sv.y), a2 = h2f(sv.z), a3 = h2f(sv.w);
    float b0 = 0.f, b1 = 0.f, b2 = 0.f, b3 = 0.f;
    int k = rs;
    for (; k + 4 <= re; k += 4) {
        int s0 = csr[k], s1 = csr[k+1], s2 = csr[k+2], s3 = csr[k+3];
        ushort4 v0 = *reinterpret_cast<const ushort4*>(z + (size_t)s0 * 32 + c0);
        ushort4 v1 = *reinterpret_cast<const ushort4*>(z + (size_t)s1 * 32 + c0);
        ushort4 v2 = *reinterpret_cast<const ushort4*>(z + (size_t)s2 * 32 + c0);
        ushort4 v3 = *reinterpret_cast<const ushort4*>(z + (size_t)s3 * 32 + c0);
        a0 += h2f(v0.x) + h2f(v2.x); a1 += h2f(v0.y) + h2f(v2.y);
        a2 += h2f(v0.z) + h2f(v2.z); a3 += h2f(v0.w) + h2f(v2.w);
        b0 += h2f(v1.x) + h2f(v3.x); b1 += h2f(v1.y) + h2f(v3.y);
        b2 += h2f(v1.z) + h2f(v3.z); b3 += h2f(v1.w) + h2f(v3.w);
    }
    for (; k < re; k++) {
        int s = csr[k];
        ushort4 v = *reinterpret_cast<const ushort4*>(z + (size_t)s * 32 + c0);
        a0 += h2f(v.x); a1 += h2f(v.y); a2 += h2f(v.z); a3 += h2f(v.w);
    }
    a0 += b0; a1 += b1; a2 += b2; a3 += b3;
    float cnt = (float)(re - rs + 1);
    zin[n][c0+0] = a0 * lsc[c0+0] + cnt * lsc[32+c0+0];
    zin[n][c0+1] = a1 * lsc[c0+1] + cnt * lsc[32+c0+1];
    zin[n][c0+2] = a2 * lsc[c0+2] + cnt * lsc[32+c0+2];
    zin[n][c0+3] = a3 * lsc[c0+3] + cnt * lsc[32+c0+3];
    __syncthreads();
    float acc0 = lbi[c0+0], acc1 = lbi[c0+1], acc2 = lbi[c0+2], acc3 = lbi[c0+3];
    #pragma unroll
    for (int c = 0; c < 32; c++) {
        float zv = zin[n][c];
        acc0 += zv * lwi[c*32 + c0+0];
        acc1 += zv * lwi[c*32 + c0+1];
        acc2 += zv * lwi[c*32 + c0+2];
        acc3 += zv * lwi[c*32 + c0+3];
    }
    yl[n][c0+0] = acc0 > 0.f ? acc0 : 0.f;
    yl[n][c0+1] = acc1 > 0.f ? acc1 : 0.f;
    yl[n][c0+2] = acc2 > 0.f ? acc2 : 0.f;
    yl[n][c0+3] = acc3 > 0.f ? acc3 : 0.f;
    __syncthreads();   // after this barrier zin is dead -> reused for stats
    float o0 = lbo[c0+0], o1 = lbo[c0+1], o2 = lbo[c0+2], o3 = lbo[c0+3];
    #pragma unroll
    for (int c = 0; c < 32; c++) {
        float yv = yl[n][c];
        o0 += yv * lwo[c*32 + c0+0];
        o1 += yv * lwo[c*32 + c0+1];
        o2 += yv * lwo[c*32 + c0+2];
        o3 += yv * lwo[c*32 + c0+3];
    }
    o0 = o0 > 0.f ? o0 : 0.f;
    o1 = o1 > 0.f ? o1 : 0.f;
    o2 = o2 > 0.f ? o2 : 0.f;
    o3 = o3 > 0.f ? o3 : 0.f;
    uint2 wout;
    wout.x = pack2(o0, o1);
    wout.y = pack2(o2, o3);
    *reinterpret_cast<uint2*>(zout + (size_t)node * 32 + c0) = wout;
    zin[n][c0+0] = o0; zin[n][c0+1] = o1; zin[n][c0+2] = o2; zin[n][c0+3] = o3;
    __syncthreads();
    if (t < 32) {
        float s = 0.f, sq = 0.f;
        for (int nn = 0; nn < 32; nn++) {
            float v = zin[nn][t];
            s += v; sq += v * v;
        }
        atomicAdd(&statsOut[t], s);
        atomicAdd(&statsOut[32 + t], sq);
    }
}

// ====== pool: batch is SORTED -> one block per graph, binary search ======
__global__ __launch_bounds__(256) void pool_seg_k(
        const unsigned short* __restrict__ z,
        const float* __restrict__ statsIn,
        const float* __restrict__ gamma, const float* __restrict__ beta,
        const int* __restrict__ batch, float* __restrict__ g) {
    __shared__ float lsc[64];
    __shared__ float part[32][33];
    int t = threadIdx.x, slot = t >> 3, q = t & 7, c0 = q * 4;
    int gr = blockIdx.x;
    if (t < 32) {
        float mean = statsIn[t] * (1.f / NN);
        float var  = statsIn[32 + t] * (1.f / NN) - mean * mean;
        float scale = gamma[t] * rsqrtf(var + BN_EPS);
        lsc[t] = scale;
        lsc[32 + t] = beta[t] - mean * scale;
    }
    int lo = 0, hi = NN;
    while (lo < hi) { int mid = (lo + hi) >> 1; if (batch[mid] < gr) lo = mid + 1; else hi = mid; }
    int start = lo;
    hi = NN;
    while (lo < hi) { int mid = (lo + hi) >> 1; if (batch[mid] < gr + 1) lo = mid + 1; else hi = mid; }
    int end = lo;
    float a0 = 0.f, a1 = 0.f, a2 = 0.f, a3 = 0.f;
    for (int i = start + slot; i < end; i += 32) {
        ushort4 v = *reinterpret_cast<const ushort4*>(z + (size_t)i * 32 + c0);
        a0 += h2f(v.x); a1 += h2f(v.y); a2 += h2f(v.z); a3 += h2f(v.w);
    }
    part[slot][c0+0] = a0; part[slot][c0+1] = a1;
    part[slot][c0+2] = a2; part[slot][c0+3] = a3;
    __syncthreads();
    if (t < 32) {
        float s = 0.f;
        for (int sl = 0; sl < 32; sl++) s += part[sl][t];
        float cnt = (float)(end - start);
        g[(size_t)gr * 32 + t] = s * lsc[t] + cnt * lsc[32 + t];
    }
}

// ---------------- head: fc1 -> relu -> fc2 -> log_softmax ----------------
__global__ __launch_bounds__(256) void head_k(
        const float* __restrict__ g,
        const float* __restrict__ fc1w, const float* __restrict__ fc1b,
        const float* __restrict__ fc2w, const float* __restrict__ fc2b,
        float* __restrict__ out) {
    __shared__ float lw1[1024], lb1[32], lw2[64], lb2[2];
    int t = threadIdx.x;
    for (int i = t; i < 1024; i += 256) lw1[i] = fc1w[i];
    if (t < 32) lb1[t] = fc1b[t];
    if (t < 64) lw2[t] = fc2w[t];
    if (t < 2) lb2[t] = fc2b[t];
    __syncthreads();
    float gv[32];
    #pragma unroll
    for (int c = 0; c < 32; c++) gv[c] = g[(size_t)t * 32 + c];
    float o0 = lb2[0], o1 = lb2[1];
    #pragma unroll 4
    for (int k = 0; k < 32; k++) {
        float a = lb1[k];
        #pragma unroll
        for (int c = 0; c < 32; c++) a += gv[c] * lw1[c * 32 + k];
        a = a > 0.f ? a : 0.f;
        o0 += a * lw2[k * 2 + 0];
        o1 += a * lw2[k * 2 + 1];
    }
    float m = fmaxf(o0, o1);
    float lse = m + logf(expf(o0 - m) + expf(o1 - m));
    out[t * 2 + 0] = o0 - lse;
    out[t * 2 + 1] = o1 - lse;
}

extern "C" void kernel_launch(void* const* d_in, const int* in_sizes, int n_in,
                              void* d_out, int out_size, void* d_ws, size_t ws_size,
                              hipStream_t stream) {
    const float* x      = (const float*)d_in[0];
    const int*   ei     = (const int*)d_in[1];
    const int*   src    = ei;
    const int*   dst    = ei + NE;
    const int*   batch  = (const int*)d_in[2];
    const float* w1_in  = (const float*)d_in[3];
    const float* b1_in  = (const float*)d_in[4];
    const float* w1_out = (const float*)d_in[5];
    const float* b1_out = (const float*)d_in[6];
    const float* ws_in  = (const float*)d_in[7];
    const float* bs_in  = (const float*)d_in[8];
    const float* ws_out = (const float*)d_in[9];
    const float* bs_out = (const float*)d_in[10];
    const float* gamma  = (const float*)d_in[11];
    const float* beta   = (const float*)d_in[12];
    const float* fc1w   = (const float*)d_in[13];
    const float* fc1b   = (const float*)d_in[14];
    const float* fc2w   = (const float*)d_in[15];
    const float* fc2b   = (const float*)d_in[16];
    float* out = (float*)d_out;

    // ---- workspace layout (16B alignment maintained) ----
    unsigned short* bufA = (unsigned short*)d_ws;        // NN*32 fp16
    unsigned short* bufB = bufA + (size_t)NN * 32;       // NN*32 fp16
    float* stats  = (float*)(bufB + (size_t)NN * 32);    // 5*64 (zeroed)
    int*   bcur   = (int*)(stats + 5 * 64);              // NPART (zeroed, adjacent)
    float* g      = (float*)(bcur + NPART);              // NG*32
    int*   perm   = (int*)(g + (size_t)NG * 32);         // NN
    int*   rowptr = perm + NN;                           // NN+4
    int*   csr    = rowptr + NN + 4;                     // NE
    unsigned int* bpk = (unsigned int*)(csr + NE);       // NPART*CAP

    // ---- zero stats + bucket cursors in one memset ----
    hipMemsetAsync(stats, 0, (size_t)(5 * 64 + NPART) * sizeof(int), stream);

    // ---- CSR build ----
    bucket_k<<<NBLK, 256, 0, stream>>>(src, dst, bcur, bpk);
    build_k<<<NPART, 256, 0, stream>>>(bcur, bpk, rowptr, csr, perm);

    // ---- layer 1 (input dim 2) -> stats[0] ----
    gmlp1_k<<<(NN + 63) / 64, 64, 0, stream>>>(x, perm, rowptr, csr,
                                               w1_in, b1_in, w1_out, b1_out, bufA, stats);

    // ---- layers 2..5 (input dim 32); BN(j) recomputed in-block ----
    const unsigned short* cur = bufA;
    unsigned short* nxt = bufB;
    for (int j = 0; j < 4; j++) {
        gmlp32_k<<<NN / 32, 256, 0, stream>>>(cur, perm, stats + j * 64,
                                              gamma + j * 32, beta + j * 32,
                                              rowptr, csr,
                                              ws_in + j * 1024, bs_in + j * 32,
                                              ws_out + j * 1024, bs_out + j * 32,
                                              nxt, stats + (j + 1) * 64);
        unsigned short* tmp = (unsigned short*)cur; cur = nxt; nxt = tmp;
    }

    // ---- pool (BN(4) in-block) + head ----
    pool_seg_k<<<NG, 256, 0, stream>>>(cur, stats + 4 * 64,
                                       gamma + 4 * 32, beta + 4 * 32, batch, g);
    head_k<<<1, 256, 0, stream>>>(g, fc1w, fc1b, fc2w, fc2b, out);
}

// Round 11
// 459.968 us; speedup vs baseline: 1.3641x; 1.2541x over previous
//
#include <hip/hip_runtime.h>
#include <math.h>

#define NN 100000
#define NE 1600000
#define NG 256
#define NPART 200
#define PS 500                        // nodes per partition (9 bits)
#define CAP 9000                      // bucket capacity (mean 8000, +11 sigma)
#define EPB 2048                      // edges per bucket_k block
#define NBLK ((NE + EPB - 1) / EPB)   // 782
#define DEGB 64                       // degree bins for counting sort
static constexpr float BN_EPS = 1e-5f;

// ---- fp16 helpers (HW RNE via v_cvt) ----
__device__ inline float h2f(unsigned short u) {
    _Float16 h; __builtin_memcpy(&h, &u, 2); return (float)h;
}
__device__ inline unsigned short f2h(float f) {
    _Float16 h = (_Float16)f; unsigned short u; __builtin_memcpy(&u, &h, 2); return u;
}
__device__ inline unsigned int pack2(float a, float b) {
    return (unsigned int)f2h(a) | ((unsigned int)f2h(b) << 16);
}

// ======= CSR stage 1: bucket edges by dst partition; packed u32 payload ======
__global__ __launch_bounds__(256) void bucket_k(const int* __restrict__ src,
                                                const int* __restrict__ dst,
                                                int* __restrict__ bcur,
                                                unsigned int* __restrict__ bpk) {
    __shared__ int cnt[NPART];
    __shared__ int base[NPART];
    int t = threadIdx.x;
    for (int i = t; i < NPART; i += 256) cnt[i] = 0;
    __syncthreads();
    int eb = blockIdx.x * EPB + t * 8;   // all-or-nothing (tail is 64x8)
    bool act = eb < NE;
    int myp[8], myr[8];
    unsigned int pk[8];
    if (act) {
        int4 d0 = *reinterpret_cast<const int4*>(dst + eb);
        int4 d1 = *reinterpret_cast<const int4*>(dst + eb + 4);
        int4 s0 = *reinterpret_cast<const int4*>(src + eb);
        int4 s1 = *reinterpret_cast<const int4*>(src + eb + 4);
        int dd[8] = {d0.x,d0.y,d0.z,d0.w,d1.x,d1.y,d1.z,d1.w};
        int ss[8] = {s0.x,s0.y,s0.z,s0.w,s1.x,s1.y,s1.z,s1.w};
        #pragma unroll
        for (int i = 0; i < 8; i++) {
            int p = dd[i] / PS;
            myp[i] = p;
            pk[i] = ((unsigned int)ss[i] << 9) | (unsigned int)(dd[i] - p * PS);
            myr[i] = atomicAdd(&cnt[p], 1);
        }
    }
    __syncthreads();
    for (int i = t; i < NPART; i += 256)
        base[i] = cnt[i] ? atomicAdd(&bcur[i], cnt[i]) : 0;
    __syncthreads();
    if (act) {
        #pragma unroll
        for (int i = 0; i < 8; i++)
            bpk[myp[i] * CAP + base[myp[i]] + myr[i]] = pk[i];
    }
}

// ==== CSR stage 2: per-partition hist + scan + deg-sort perm + place =========
__global__ __launch_bounds__(256) void build_k(const int* __restrict__ bcur,
                                               const unsigned int* __restrict__ bpk,
                                               int* __restrict__ rowptr,
                                               int* __restrict__ csr,
                                               int* __restrict__ perm) {
    __shared__ int hist[PS];          // histogram -> cursor
    __shared__ int allc[NPART];
    __shared__ int psum[256];
    __shared__ int bc[DEGB];
    int p = blockIdx.x, t = threadIdx.x;
    int lo = p * PS;
    if (t < NPART) allc[t] = bcur[t];
    for (int i = t; i < PS; i += 256) hist[i] = 0;
    if (t < DEGB) bc[t] = 0;
    __syncthreads();
    int base = 0;
    for (int q = 0; q < p; q++) base += allc[q];
    int cnt = allc[p];
    const unsigned int* bp = bpk + p * CAP;
    const uint4* bp4 = reinterpret_cast<const uint4*>(bp);
    int n4 = cnt >> 2;
    for (int i = t; i < n4; i += 256) {
        uint4 v = bp4[i];
        atomicAdd(&hist[v.x & 511u], 1);
        atomicAdd(&hist[v.y & 511u], 1);
        atomicAdd(&hist[v.z & 511u], 1);
        atomicAdd(&hist[v.w & 511u], 1);
    }
    for (int i = 4 * n4 + t; i < cnt; i += 256) atomicAdd(&hist[bp[i] & 511u], 1);
    __syncthreads();
    int j0 = t * 2;
    int d0v = 0, d1v = 0, tsum = 0;
    if (j0 < PS) {
        d0v = hist[j0]; d1v = hist[j0 + 1];
        tsum = d0v + d1v;
        atomicAdd(&bc[d0v < DEGB ? d0v : DEGB - 1], 1);
        atomicAdd(&bc[d1v < DEGB ? d1v : DEGB - 1], 1);
    }
    psum[t] = tsum;
    __syncthreads();
    for (int off = 1; off < 256; off <<= 1) {
        int v = (t >= off) ? psum[t - off] : 0;
        __syncthreads();
        psum[t] += v;
        __syncthreads();
    }
    int texcl = psum[t] - tsum;
    if (j0 < PS) {
        int run = base + texcl;
        hist[j0] = run; rowptr[lo + j0] = run; run += d0v;
        hist[j0 + 1] = run; rowptr[lo + j0 + 1] = run; run += d1v;
    }
    if (p == NPART - 1 && t == 0) rowptr[NN] = base + cnt;
    __syncthreads();
    if (t == 0) {
        int run = 0;
        #pragma unroll
        for (int b = 0; b < DEGB; b++) { int c = bc[b]; bc[b] = run; run += c; }
    }
    __syncthreads();
    if (j0 < PS) {
        int r0 = atomicAdd(&bc[d0v < DEGB ? d0v : DEGB - 1], 1);
        perm[lo + r0] = lo + j0;
        int r1 = atomicAdd(&bc[d1v < DEGB ? d1v : DEGB - 1], 1);
        perm[lo + r1] = lo + j0 + 1;
    }
    __syncthreads();
    for (int i = t; i < n4; i += 256) {
        uint4 v = bp4[i];
        csr[atomicAdd(&hist[v.x & 511u], 1)] = v.x >> 9;
        csr[atomicAdd(&hist[v.y & 511u], 1)] = v.y >> 9;
        csr[atomicAdd(&hist[v.z & 511u], 1)] = v.z >> 9;
        csr[atomicAdd(&hist[v.w & 511u], 1)] = v.w >> 9;
    }
    for (int i = 4 * n4 + t; i < cnt; i += 256)
        csr[atomicAdd(&hist[bp[i] & 511u], 1)] = bp[i] >> 9;
}

// ============== layer 1: gather(d=2) + MLP 2->32->32 + stats0 ==============
__global__ __launch_bounds__(64) void gmlp1_k(
        const float* __restrict__ x, const int* __restrict__ perm,
        const int* __restrict__ rowptr, const int* __restrict__ csr,
        const float* __restrict__ w_in, const float* __restrict__ b_in,
        const float* __restrict__ w_out, const float* __restrict__ b_out,
        unsigned short* __restrict__ zout, float* __restrict__ stats) {
    __shared__ float lwi[64], lbi[32], lwo[1024], lbo[32];
    __shared__ float zl[64][33];
    int t = threadIdx.x;
    lwi[t] = w_in[t];
    if (t < 32) { lbi[t] = b_in[t]; lbo[t] = b_out[t]; }
    for (int i = t; i < 1024; i += 64) lwo[i] = w_out[i];
    __syncthreads();
    int gid = blockIdx.x * 64 + t;
    if (gid < NN) {
        int node = perm[gid];
        float2 self = *reinterpret_cast<const float2*>(x + 2 * (size_t)node);
        float h0 = self.x, h1 = self.y;
        float g0 = 0.f, g1 = 0.f;
        int rs = rowptr[node], re = rowptr[node + 1];
        int k = rs;
        for (; k + 4 <= re; k += 4) {
            int s0 = csr[k], s1 = csr[k+1], s2 = csr[k+2], s3 = csr[k+3];
            float2 v0 = *reinterpret_cast<const float2*>(x + 2 * (size_t)s0);
            float2 v1 = *reinterpret_cast<const float2*>(x + 2 * (size_t)s1);
            float2 v2 = *reinterpret_cast<const float2*>(x + 2 * (size_t)s2);
            float2 v3 = *reinterpret_cast<const float2*>(x + 2 * (size_t)s3);
            h0 += v0.x + v2.x; h1 += v0.y + v2.y;
            g0 += v1.x + v3.x; g1 += v1.y + v3.y;
        }
        for (; k < re; k++) {
            int s = csr[k];
            float2 v = *reinterpret_cast<const float2*>(x + 2 * (size_t)s);
            h0 += v.x; h1 += v.y;
        }
        h0 += g0; h1 += g1;
        float y[32];
        #pragma unroll
        for (int kk = 0; kk < 32; kk++) {
            float a = lbi[kk] + h0 * lwi[kk] + h1 * lwi[32 + kk];
            y[kk] = a > 0.f ? a : 0.f;
        }
        float z[32];
        #pragma unroll 4
        for (int kk = 0; kk < 32; kk++) {
            float a = lbo[kk];
            #pragma unroll
            for (int c = 0; c < 32; c++) a += y[c] * lwo[c * 32 + kk];
            z[kk] = a > 0.f ? a : 0.f;
        }
        uint4* zo = reinterpret_cast<uint4*>(zout + (size_t)node * 32);
        #pragma unroll
        for (int kk = 0; kk < 4; kk++) {
            uint4 w;
            w.x = pack2(z[8*kk+0], z[8*kk+1]);
            w.y = pack2(z[8*kk+2], z[8*kk+3]);
            w.z = pack2(z[8*kk+4], z[8*kk+5]);
            w.w = pack2(z[8*kk+6], z[8*kk+7]);
            zo[kk] = w;
        }
        #pragma unroll
        for (int kk = 0; kk < 32; kk++) zl[t][kk] = z[kk];
    } else {
        for (int kk = 0; kk < 32; kk++) zl[t][kk] = 0.f;
    }
    __syncthreads();
    if (t < 32) {
        float s = 0.f, sq = 0.f;
        for (int n = 0; n < 64; n++) { float v = zl[n][t]; s += v; sq += v * v; }
        atomicAdd(&stats[t], s);
        atomicAdd(&stats[32 + t], sq);
    }
}

// ======= heavy layer v2: 4 lanes/node (16 rows in flight per wave) ==========
// 256 threads = 64 nodes x 4 lanes; lane owns 8 channels (one 16B load/row).
// zin LDS buffer reused across phases: gather-sum -> y -> o(stats).
__global__ __launch_bounds__(256) void gmlp32_k(
        const unsigned short* __restrict__ z, const int* __restrict__ perm,
        const float* __restrict__ statsIn,
        const float* __restrict__ gamma, const float* __restrict__ beta,
        const int* __restrict__ rowptr, const int* __restrict__ csr,
        const float* __restrict__ w_in, const float* __restrict__ b_in,
        const float* __restrict__ w_out, const float* __restrict__ b_out,
        unsigned short* __restrict__ zout, float* __restrict__ statsOut) {
    __shared__ float lwi[1024], lwo[1024], lbi[32], lbo[32], lsc[64];
    __shared__ float zin[64][33];
    int t = threadIdx.x;
    int n = t >> 2, q = t & 3, c0 = q * 8;
    for (int i = t; i < 1024; i += 256) { lwi[i] = w_in[i]; lwo[i] = w_out[i]; }
    if (t < 32) {
        lbi[t] = b_in[t]; lbo[t] = b_out[t];
        float mean = statsIn[t] * (1.f / NN);
        float var  = statsIn[32 + t] * (1.f / NN) - mean * mean;
        float scale = gamma[t] * rsqrtf(var + BN_EPS);
        lsc[t] = scale;
        lsc[32 + t] = beta[t] - mean * scale;
    }
    __syncthreads();
    int gid = blockIdx.x * 64 + n;
    bool act = gid < NN;
    int node = act ? perm[gid] : 0;
    float a[8] = {0,0,0,0,0,0,0,0};
    float cntf = 0.f;
    if (act) {
        int rs = rowptr[node], re = rowptr[node + 1];
        cntf = (float)(re - rs + 1);
        // self row
        uint4 sv = *reinterpret_cast<const uint4*>(z + (size_t)node * 32 + c0);
        const unsigned short* sp = reinterpret_cast<const unsigned short*>(&sv);
        #pragma unroll
        for (int j = 0; j < 8; j++) a[j] = h2f(sp[j]);
        float b[8] = {0,0,0,0,0,0,0,0};
        int k = rs;
        for (; k + 4 <= re; k += 4) {
            int s0 = csr[k], s1 = csr[k+1], s2 = csr[k+2], s3 = csr[k+3];
            uint4 v0 = *reinterpret_cast<const uint4*>(z + (size_t)s0 * 32 + c0);
            uint4 v1 = *reinterpret_cast<const uint4*>(z + (size_t)s1 * 32 + c0);
            uint4 v2 = *reinterpret_cast<const uint4*>(z + (size_t)s2 * 32 + c0);
            uint4 v3 = *reinterpret_cast<const uint4*>(z + (size_t)s3 * 32 + c0);
            const unsigned short* p0 = reinterpret_cast<const unsigned short*>(&v0);
            const unsigned short* p1 = reinterpret_cast<const unsigned short*>(&v1);
            const unsigned short* p2 = reinterpret_cast<const unsigned short*>(&v2);
            const unsigned short* p3 = reinterpret_cast<const unsigned short*>(&v3);
            #pragma unroll
            for (int j = 0; j < 8; j++) {
                a[j] += h2f(p0[j]) + h2f(p2[j]);
                b[j] += h2f(p1[j]) + h2f(p3[j]);
            }
        }
        for (; k < re; k++) {
            int s = csr[k];
            uint4 v = *reinterpret_cast<const uint4*>(z + (size_t)s * 32 + c0);
            const unsigned short* pp = reinterpret_cast<const unsigned short*>(&v);
            #pragma unroll
            for (int j = 0; j < 8; j++) a[j] += h2f(pp[j]);
        }
        #pragma unroll
        for (int j = 0; j < 8; j++) a[j] += b[j];
    }
    #pragma unroll
    for (int j = 0; j < 8; j++)
        zin[n][c0 + j] = act ? (a[j] * lsc[c0 + j] + cntf * lsc[32 + c0 + j]) : 0.f;
    __syncthreads();
    // GEMM1: y = relu(zin @ w_in + b_in), thread computes 8 channels
    float y[8];
    #pragma unroll
    for (int j = 0; j < 8; j++) y[j] = lbi[c0 + j];
    #pragma unroll
    for (int c = 0; c < 32; c++) {
        float zv = zin[n][c];
        #pragma unroll
        for (int j = 0; j < 8; j++) y[j] += zv * lwi[c * 32 + c0 + j];
    }
    #pragma unroll
    for (int j = 0; j < 8; j++) y[j] = y[j] > 0.f ? y[j] : 0.f;
    __syncthreads();   // all zin reads done -> safe to overwrite
    #pragma unroll
    for (int j = 0; j < 8; j++) zin[n][c0 + j] = y[j];
    __syncthreads();
    // GEMM2: o = relu(y @ w_out + b_out)
    float o[8];
    #pragma unroll
    for (int j = 0; j < 8; j++) o[j] = lbo[c0 + j];
    #pragma unroll
    for (int c = 0; c < 32; c++) {
        float yv = zin[n][c];
        #pragma unroll
        for (int j = 0; j < 8; j++) o[j] += yv * lwo[c * 32 + c0 + j];
    }
    #pragma unroll
    for (int j = 0; j < 8; j++) o[j] = o[j] > 0.f ? o[j] : 0.f;
    if (act) {
        uint4 w;
        w.x = pack2(o[0], o[1]);
        w.y = pack2(o[2], o[3]);
        w.z = pack2(o[4], o[5]);
        w.w = pack2(o[6], o[7]);
        *reinterpret_cast<uint4*>(zout + (size_t)node * 32 + c0) = w;
    }
    __syncthreads();   // all zin(y) reads done -> safe to overwrite
    #pragma unroll
    for (int j = 0; j < 8; j++) zin[n][c0 + j] = act ? o[j] : 0.f;
    __syncthreads();
    if (t < 32) {
        float s = 0.f, sq = 0.f;
        for (int nn = 0; nn < 64; nn++) {
            float v = zin[nn][t];
            s += v; sq += v * v;
        }
        atomicAdd(&statsOut[t], s);
        atomicAdd(&statsOut[32 + t], sq);
    }
}

// ====== pool: batch is SORTED -> one block per graph, binary search ======
__global__ __launch_bounds__(256) void pool_seg_k(
        const unsigned short* __restrict__ z,
        const float* __restrict__ statsIn,
        const float* __restrict__ gamma, const float* __restrict__ beta,
        const int* __restrict__ batch, float* __restrict__ g) {
    __shared__ float lsc[64];
    __shared__ float part[32][33];
    int t = threadIdx.x, slot = t >> 3, q = t & 7, c0 = q * 4;
    int gr = blockIdx.x;
    if (t < 32) {
        float mean = statsIn[t] * (1.f / NN);
        float var  = statsIn[32 + t] * (1.f / NN) - mean * mean;
        float scale = gamma[t] * rsqrtf(var + BN_EPS);
        lsc[t] = scale;
        lsc[32 + t] = beta[t] - mean * scale;
    }
    int lo = 0, hi = NN;
    while (lo < hi) { int mid = (lo + hi) >> 1; if (batch[mid] < gr) lo = mid + 1; else hi = mid; }
    int start = lo;
    hi = NN;
    while (lo < hi) { int mid = (lo + hi) >> 1; if (batch[mid] < gr + 1) lo = mid + 1; else hi = mid; }
    int end = lo;
    float a0 = 0.f, a1 = 0.f, a2 = 0.f, a3 = 0.f;
    for (int i = start + slot; i < end; i += 32) {
        ushort4 v = *reinterpret_cast<const ushort4*>(z + (size_t)i * 32 + c0);
        a0 += h2f(v.x); a1 += h2f(v.y); a2 += h2f(v.z); a3 += h2f(v.w);
    }
    part[slot][c0+0] = a0; part[slot][c0+1] = a1;
    part[slot][c0+2] = a2; part[slot][c0+3] = a3;
    __syncthreads();
    if (t < 32) {
        float s = 0.f;
        for (int sl = 0; sl < 32; sl++) s += part[sl][t];
        float cnt = (float)(end - start);
        g[(size_t)gr * 32 + t] = s * lsc[t] + cnt * lsc[32 + t];
    }
}

// ---------------- head: fc1 -> relu -> fc2 -> log_softmax ----------------
__global__ __launch_bounds__(256) void head_k(
        const float* __restrict__ g,
        const float* __restrict__ fc1w, const float* __restrict__ fc1b,
        const float* __restrict__ fc2w, const float* __restrict__ fc2b,
        float* __restrict__ out) {
    __shared__ float lw1[1024], lb1[32], lw2[64], lb2[2];
    int t = threadIdx.x;
    for (int i = t; i < 1024; i += 256) lw1[i] = fc1w[i];
    if (t < 32) lb1[t] = fc1b[t];
    if (t < 64) lw2[t] = fc2w[t];
    if (t < 2) lb2[t] = fc2b[t];
    __syncthreads();
    float gv[32];
    #pragma unroll
    for (int c = 0; c < 32; c++) gv[c] = g[(size_t)t * 32 + c];
    float o0 = lb2[0], o1 = lb2[1];
    #pragma unroll 4
    for (int k = 0; k < 32; k++) {
        float a = lb1[k];
        #pragma unroll
        for (int c = 0; c < 32; c++) a += gv[c] * lw1[c * 32 + k];
        a = a > 0.f ? a : 0.f;
        o0 += a * lw2[k * 2 + 0];
        o1 += a * lw2[k * 2 + 1];
    }
    float m = fmaxf(o0, o1);
    float lse = m + logf(expf(o0 - m) + expf(o1 - m));
    out[t * 2 + 0] = o0 - lse;
    out[t * 2 + 1] = o1 - lse;
}

extern "C" void kernel_launch(void* const* d_in, const int* in_sizes, int n_in,
                              void* d_out, int out_size, void* d_ws, size_t ws_size,
                              hipStream_t stream) {
    const float* x      = (const float*)d_in[0];
    const int*   ei     = (const int*)d_in[1];
    const int*   src    = ei;
    const int*   dst    = ei + NE;
    const int*   batch  = (const int*)d_in[2];
    const float* w1_in  = (const float*)d_in[3];
    const float* b1_in  = (const float*)d_in[4];
    const float* w1_out = (const float*)d_in[5];
    const float* b1_out = (const float*)d_in[6];
    const float* ws_in  = (const float*)d_in[7];
    const float* bs_in  = (const float*)d_in[8];
    const float* ws_out = (const float*)d_in[9];
    const float* bs_out = (const float*)d_in[10];
    const float* gamma  = (const float*)d_in[11];
    const float* beta   = (const float*)d_in[12];
    const float* fc1w   = (const float*)d_in[13];
    const float* fc1b   = (const float*)d_in[14];
    const float* fc2w   = (const float*)d_in[15];
    const float* fc2b   = (const float*)d_in[16];
    float* out = (float*)d_out;

    // ---- workspace layout (16B alignment maintained) ----
    unsigned short* bufA = (unsigned short*)d_ws;        // NN*32 fp16
    unsigned short* bufB = bufA + (size_t)NN * 32;       // NN*32 fp16
    float* stats  = (float*)(bufB + (size_t)NN * 32);    // 5*64 (zeroed)
    int*   bcur   = (int*)(stats + 5 * 64);              // NPART (zeroed, adjacent)
    float* g      = (float*)(bcur + NPART);              // NG*32
    int*   perm   = (int*)(g + (size_t)NG * 32);         // NN
    int*   rowptr = perm + NN;                           // NN+4
    int*   csr    = rowptr + NN + 4;                     // NE
    unsigned int* bpk = (unsigned int*)(csr + NE);       // NPART*CAP

    // ---- zero stats + bucket cursors in one memset ----
    hipMemsetAsync(stats, 0, (size_t)(5 * 64 + NPART) * sizeof(int), stream);

    // ---- CSR build ----
    bucket_k<<<NBLK, 256, 0, stream>>>(src, dst, bcur, bpk);
    build_k<<<NPART, 256, 0, stream>>>(bcur, bpk, rowptr, csr, perm);

    // ---- layer 1 (input dim 2) -> stats[0] ----
    gmlp1_k<<<(NN + 63) / 64, 64, 0, stream>>>(x, perm, rowptr, csr,
                                               w1_in, b1_in, w1_out, b1_out, bufA, stats);

    // ---- layers 2..5 (input dim 32); BN(j) recomputed in-block ----
    const unsigned short* cur = bufA;
    unsigned short* nxt = bufB;
    for (int j = 0; j < 4; j++) {
        gmlp32_k<<<(NN + 63) / 64, 256, 0, stream>>>(cur, perm, stats + j * 64,
                                              gamma + j * 32, beta + j * 32,
                                              rowptr, csr,
                                              ws_in + j * 1024, bs_in + j * 32,
                                              ws_out + j * 1024, bs_out + j * 32,
                                              nxt, stats + (j + 1) * 64);
        unsigned short* tmp = (unsigned short*)cur; cur = nxt; nxt = tmp;
    }

    // ---- pool (BN(4) in-block) + head ----
    pool_seg_k<<<NG, 256, 0, stream>>>(cur, stats + 4 * 64,
                                       gamma + 4 * 32, beta + 4 * 32, batch, g);
    head_k<<<1, 256, 0, stream>>>(g, fc1w, fc1b, fc2w, fc2b, out);
}

// Round 12
// 413.328 us; speedup vs baseline: 1.5180x; 1.1128x over previous
//
#include <hip/hip_runtime.h>
#include <math.h>

#define NN 100000
#define NE 1600000
#define NG 256
#define NPART 200
#define PS 500                        // nodes per partition (9 bits)
#define CAP 9000                      // bucket capacity (mean 8000, +11 sigma)
#define EPB 2048                      // edges per bucket_k block
#define NBLK ((NE + EPB - 1) / EPB)   // 782
#define DEGB 64                       // degree bins for counting sort
static constexpr float BN_EPS = 1e-5f;

// ---- fp16 helpers (HW RNE via v_cvt) ----
__device__ inline float h2f(unsigned short u) {
    _Float16 h; __builtin_memcpy(&h, &u, 2); return (float)h;
}
__device__ inline unsigned short f2h(float f) {
    _Float16 h = (_Float16)f; unsigned short u; __builtin_memcpy(&u, &h, 2); return u;
}
__device__ inline unsigned int pack2(float a, float b) {
    return (unsigned int)f2h(a) | ((unsigned int)f2h(b) << 16);
}

// ======= CSR stage 1: bucket edges by dst partition; packed u32 payload ======
__global__ __launch_bounds__(256) void bucket_k(const int* __restrict__ src,
                                                const int* __restrict__ dst,
                                                int* __restrict__ bcur,
                                                unsigned int* __restrict__ bpk) {
    __shared__ int cnt[NPART];
    __shared__ int base[NPART];
    int t = threadIdx.x;
    for (int i = t; i < NPART; i += 256) cnt[i] = 0;
    __syncthreads();
    int eb = blockIdx.x * EPB + t * 8;   // all-or-nothing (tail is 64x8)
    bool act = eb < NE;
    int myp[8], myr[8];
    unsigned int pk[8];
    if (act) {
        int4 d0 = *reinterpret_cast<const int4*>(dst + eb);
        int4 d1 = *reinterpret_cast<const int4*>(dst + eb + 4);
        int4 s0 = *reinterpret_cast<const int4*>(src + eb);
        int4 s1 = *reinterpret_cast<const int4*>(src + eb + 4);
        int dd[8] = {d0.x,d0.y,d0.z,d0.w,d1.x,d1.y,d1.z,d1.w};
        int ss[8] = {s0.x,s0.y,s0.z,s0.w,s1.x,s1.y,s1.z,s1.w};
        #pragma unroll
        for (int i = 0; i < 8; i++) {
            int p = dd[i] / PS;
            myp[i] = p;
            pk[i] = ((unsigned int)ss[i] << 9) | (unsigned int)(dd[i] - p * PS);
            myr[i] = atomicAdd(&cnt[p], 1);
        }
    }
    __syncthreads();
    for (int i = t; i < NPART; i += 256)
        base[i] = cnt[i] ? atomicAdd(&bcur[i], cnt[i]) : 0;
    __syncthreads();
    if (act) {
        #pragma unroll
        for (int i = 0; i < 8; i++)
            bpk[myp[i] * CAP + base[myp[i]] + myr[i]] = pk[i];
    }
}

// ==== CSR stage 2: per-partition hist + scan + deg-sort perm + place =========
__global__ __launch_bounds__(256) void build_k(const int* __restrict__ bcur,
                                               const unsigned int* __restrict__ bpk,
                                               int* __restrict__ rowptr,
                                               int* __restrict__ csr,
                                               int* __restrict__ perm) {
    __shared__ int hist[PS];          // histogram -> cursor
    __shared__ int allc[NPART];
    __shared__ int psum[256];
    __shared__ int bc[DEGB];
    int p = blockIdx.x, t = threadIdx.x;
    int lo = p * PS;
    if (t < NPART) allc[t] = bcur[t];
    for (int i = t; i < PS; i += 256) hist[i] = 0;
    if (t < DEGB) bc[t] = 0;
    __syncthreads();
    int base = 0;
    for (int q = 0; q < p; q++) base += allc[q];
    int cnt = allc[p];
    const unsigned int* bp = bpk + p * CAP;
    const uint4* bp4 = reinterpret_cast<const uint4*>(bp);
    int n4 = cnt >> 2;
    for (int i = t; i < n4; i += 256) {
        uint4 v = bp4[i];
        atomicAdd(&hist[v.x & 511u], 1);
        atomicAdd(&hist[v.y & 511u], 1);
        atomicAdd(&hist[v.z & 511u], 1);
        atomicAdd(&hist[v.w & 511u], 1);
    }
    for (int i = 4 * n4 + t; i < cnt; i += 256) atomicAdd(&hist[bp[i] & 511u], 1);
    __syncthreads();
    int j0 = t * 2;
    int d0v = 0, d1v = 0, tsum = 0;
    if (j0 < PS) {
        d0v = hist[j0]; d1v = hist[j0 + 1];
        tsum = d0v + d1v;
        atomicAdd(&bc[d0v < DEGB ? d0v : DEGB - 1], 1);
        atomicAdd(&bc[d1v < DEGB ? d1v : DEGB - 1], 1);
    }
    psum[t] = tsum;
    __syncthreads();
    for (int off = 1; off < 256; off <<= 1) {
        int v = (t >= off) ? psum[t - off] : 0;
        __syncthreads();
        psum[t] += v;
        __syncthreads();
    }
    int texcl = psum[t] - tsum;
    if (j0 < PS) {
        int run = base + texcl;
        hist[j0] = run; rowptr[lo + j0] = run; run += d0v;
        hist[j0 + 1] = run; rowptr[lo + j0 + 1] = run; run += d1v;
    }
    if (p == NPART - 1 && t == 0) rowptr[NN] = base + cnt;
    __syncthreads();
    if (t == 0) {
        int run = 0;
        #pragma unroll
        for (int b = 0; b < DEGB; b++) { int c = bc[b]; bc[b] = run; run += c; }
    }
    __syncthreads();
    if (j0 < PS) {
        int r0 = atomicAdd(&bc[d0v < DEGB ? d0v : DEGB - 1], 1);
        perm[lo + r0] = lo + j0;
        int r1 = atomicAdd(&bc[d1v < DEGB ? d1v : DEGB - 1], 1);
        perm[lo + r1] = lo + j0 + 1;
    }
    __syncthreads();
    for (int i = t; i < n4; i += 256) {
        uint4 v = bp4[i];
        csr[atomicAdd(&hist[v.x & 511u], 1)] = v.x >> 9;
        csr[atomicAdd(&hist[v.y & 511u], 1)] = v.y >> 9;
        csr[atomicAdd(&hist[v.z & 511u], 1)] = v.z >> 9;
        csr[atomicAdd(&hist[v.w & 511u], 1)] = v.w >> 9;
    }
    for (int i = 4 * n4 + t; i < cnt; i += 256)
        csr[atomicAdd(&hist[bp[i] & 511u], 1)] = bp[i] >> 9;
}

// ============== layer 1: gather(d=2) + MLP 2->32->32 + stats0 ==============
__global__ __launch_bounds__(64) void gmlp1_k(
        const float* __restrict__ x, const int* __restrict__ perm,
        const int* __restrict__ rowptr, const int* __restrict__ csr,
        const float* __restrict__ w_in, const float* __restrict__ b_in,
        const float* __restrict__ w_out, const float* __restrict__ b_out,
        unsigned short* __restrict__ zout, float* __restrict__ stats) {
    __shared__ float lwi[64], lbi[32], lwo[1024], lbo[32];
    __shared__ float zl[64][33];
    int t = threadIdx.x;
    lwi[t] = w_in[t];
    if (t < 32) { lbi[t] = b_in[t]; lbo[t] = b_out[t]; }
    for (int i = t; i < 1024; i += 64) lwo[i] = w_out[i];
    __syncthreads();
    int gid = blockIdx.x * 64 + t;
    if (gid < NN) {
        int node = perm[gid];
        float2 self = *reinterpret_cast<const float2*>(x + 2 * (size_t)node);
        float h0 = self.x, h1 = self.y;
        float g0 = 0.f, g1 = 0.f;
        int rs = rowptr[node], re = rowptr[node + 1];
        int k = rs;
        for (; k + 4 <= re; k += 4) {
            int s0 = csr[k], s1 = csr[k+1], s2 = csr[k+2], s3 = csr[k+3];
            float2 v0 = *reinterpret_cast<const float2*>(x + 2 * (size_t)s0);
            float2 v1 = *reinterpret_cast<const float2*>(x + 2 * (size_t)s1);
            float2 v2 = *reinterpret_cast<const float2*>(x + 2 * (size_t)s2);
            float2 v3 = *reinterpret_cast<const float2*>(x + 2 * (size_t)s3);
            h0 += v0.x + v2.x; h1 += v0.y + v2.y;
            g0 += v1.x + v3.x; g1 += v1.y + v3.y;
        }
        for (; k < re; k++) {
            int s = csr[k];
            float2 v = *reinterpret_cast<const float2*>(x + 2 * (size_t)s);
            h0 += v.x; h1 += v.y;
        }
        h0 += g0; h1 += g1;
        float y[32];
        #pragma unroll
        for (int kk = 0; kk < 32; kk++) {
            float a = lbi[kk] + h0 * lwi[kk] + h1 * lwi[32 + kk];
            y[kk] = a > 0.f ? a : 0.f;
        }
        float z[32];
        #pragma unroll 4
        for (int kk = 0; kk < 32; kk++) {
            float a = lbo[kk];
            #pragma unroll
            for (int c = 0; c < 32; c++) a += y[c] * lwo[c * 32 + kk];
            z[kk] = a > 0.f ? a : 0.f;
        }
        uint4* zo = reinterpret_cast<uint4*>(zout + (size_t)node * 32);
        #pragma unroll
        for (int kk = 0; kk < 4; kk++) {
            uint4 w;
            w.x = pack2(z[8*kk+0], z[8*kk+1]);
            w.y = pack2(z[8*kk+2], z[8*kk+3]);
            w.z = pack2(z[8*kk+4], z[8*kk+5]);
            w.w = pack2(z[8*kk+6], z[8*kk+7]);
            zo[kk] = w;
        }
        #pragma unroll
        for (int kk = 0; kk < 32; kk++) zl[t][kk] = z[kk];
    } else {
        for (int kk = 0; kk < 32; kk++) zl[t][kk] = 0.f;
    }
    __syncthreads();
    if (t < 32) {
        float s = 0.f, sq = 0.f;
        for (int n = 0; n < 64; n++) { float v = zl[n][t]; s += v; sq += v * v; }
        atomicAdd(&stats[t], s);
        atomicAdd(&stats[32 + t], sq);
    }
}

// ======= heavy layer v3: 2 lanes/node, 128 nodes/block, 4-row unroll ========
// Wave = 32 nodes; per unrolled iter each lane has 4 rows x 2 uint4 in flight
// -> up to 128 row-lines in flight per wave. zin LDS reused across phases.
__global__ __launch_bounds__(256) void gmlp32_k(
        const unsigned short* __restrict__ z, const int* __restrict__ perm,
        const float* __restrict__ statsIn,
        const float* __restrict__ gamma, const float* __restrict__ beta,
        const int* __restrict__ rowptr, const int* __restrict__ csr,
        const float* __restrict__ w_in, const float* __restrict__ b_in,
        const float* __restrict__ w_out, const float* __restrict__ b_out,
        unsigned short* __restrict__ zout, float* __restrict__ statsOut) {
    __shared__ float lwi[1024], lwo[1024], lbi[32], lbo[32], lsc[64];
    __shared__ float zin[128][33];
    int t = threadIdx.x;
    int n = t >> 1, q = t & 1, c0 = q * 16;
    for (int i = t; i < 1024; i += 256) { lwi[i] = w_in[i]; lwo[i] = w_out[i]; }
    if (t < 32) {
        lbi[t] = b_in[t]; lbo[t] = b_out[t];
        float mean = statsIn[t] * (1.f / NN);
        float var  = statsIn[32 + t] * (1.f / NN) - mean * mean;
        float scale = gamma[t] * rsqrtf(var + BN_EPS);
        lsc[t] = scale;
        lsc[32 + t] = beta[t] - mean * scale;
    }
    __syncthreads();
    int gid = blockIdx.x * 128 + n;
    bool act = gid < NN;
    int node = act ? perm[gid] : 0;
    float a[16];
    #pragma unroll
    for (int j = 0; j < 16; j++) a[j] = 0.f;
    float cntf = 0.f;
    if (act) {
        int rs = rowptr[node], re = rowptr[node + 1];
        cntf = (float)(re - rs + 1);
        const unsigned short* zb = z + (size_t)node * 32 + c0;
        uint4 sa = *reinterpret_cast<const uint4*>(zb);
        uint4 sb = *reinterpret_cast<const uint4*>(zb + 8);
        const unsigned short* pa = reinterpret_cast<const unsigned short*>(&sa);
        const unsigned short* pb = reinterpret_cast<const unsigned short*>(&sb);
        #pragma unroll
        for (int j = 0; j < 8; j++) { a[j] = h2f(pa[j]); a[8 + j] = h2f(pb[j]); }
        int k = rs;
        for (; k + 4 <= re; k += 4) {
            int s0 = csr[k], s1 = csr[k + 1], s2 = csr[k + 2], s3 = csr[k + 3];
            const unsigned short* r0 = z + (size_t)s0 * 32 + c0;
            const unsigned short* r1 = z + (size_t)s1 * 32 + c0;
            const unsigned short* r2 = z + (size_t)s2 * 32 + c0;
            const unsigned short* r3 = z + (size_t)s3 * 32 + c0;
            uint4 v0a = *reinterpret_cast<const uint4*>(r0);
            uint4 v0b = *reinterpret_cast<const uint4*>(r0 + 8);
            uint4 v1a = *reinterpret_cast<const uint4*>(r1);
            uint4 v1b = *reinterpret_cast<const uint4*>(r1 + 8);
            uint4 v2a = *reinterpret_cast<const uint4*>(r2);
            uint4 v2b = *reinterpret_cast<const uint4*>(r2 + 8);
            uint4 v3a = *reinterpret_cast<const uint4*>(r3);
            uint4 v3b = *reinterpret_cast<const uint4*>(r3 + 8);
            const unsigned short* q0a = reinterpret_cast<const unsigned short*>(&v0a);
            const unsigned short* q0b = reinterpret_cast<const unsigned short*>(&v0b);
            const unsigned short* q1a = reinterpret_cast<const unsigned short*>(&v1a);
            const unsigned short* q1b = reinterpret_cast<const unsigned short*>(&v1b);
            const unsigned short* q2a = reinterpret_cast<const unsigned short*>(&v2a);
            const unsigned short* q2b = reinterpret_cast<const unsigned short*>(&v2b);
            const unsigned short* q3a = reinterpret_cast<const unsigned short*>(&v3a);
            const unsigned short* q3b = reinterpret_cast<const unsigned short*>(&v3b);
            #pragma unroll
            for (int j = 0; j < 8; j++) {
                a[j]     += (h2f(q0a[j]) + h2f(q1a[j])) + (h2f(q2a[j]) + h2f(q3a[j]));
                a[8 + j] += (h2f(q0b[j]) + h2f(q1b[j])) + (h2f(q2b[j]) + h2f(q3b[j]));
            }
        }
        for (; k < re; k++) {
            int s = csr[k];
            const unsigned short* r = z + (size_t)s * 32 + c0;
            uint4 va = *reinterpret_cast<const uint4*>(r);
            uint4 vb = *reinterpret_cast<const uint4*>(r + 8);
            const unsigned short* qa = reinterpret_cast<const unsigned short*>(&va);
            const unsigned short* qb = reinterpret_cast<const unsigned short*>(&vb);
            #pragma unroll
            for (int j = 0; j < 8; j++) { a[j] += h2f(qa[j]); a[8 + j] += h2f(qb[j]); }
        }
    }
    #pragma unroll
    for (int j = 0; j < 16; j++)
        zin[n][c0 + j] = act ? (a[j] * lsc[c0 + j] + cntf * lsc[32 + c0 + j]) : 0.f;
    __syncthreads();
    // GEMM1: y = relu(zin @ w_in + b_in); lane computes 16 channels
    float y[16];
    #pragma unroll
    for (int j = 0; j < 16; j++) y[j] = lbi[c0 + j];
    #pragma unroll
    for (int c = 0; c < 32; c++) {
        float zv = zin[n][c];
        #pragma unroll
        for (int j = 0; j < 16; j++) y[j] += zv * lwi[c * 32 + c0 + j];
    }
    #pragma unroll
    for (int j = 0; j < 16; j++) y[j] = y[j] > 0.f ? y[j] : 0.f;
    __syncthreads();   // all zin reads done -> safe to overwrite
    #pragma unroll
    for (int j = 0; j < 16; j++) zin[n][c0 + j] = y[j];
    __syncthreads();
    // GEMM2: o = relu(y @ w_out + b_out)
    float o[16];
    #pragma unroll
    for (int j = 0; j < 16; j++) o[j] = lbo[c0 + j];
    #pragma unroll
    for (int c = 0; c < 32; c++) {
        float yv = zin[n][c];
        #pragma unroll
        for (int j = 0; j < 16; j++) o[j] += yv * lwo[c * 32 + c0 + j];
    }
    #pragma unroll
    for (int j = 0; j < 16; j++) o[j] = o[j] > 0.f ? o[j] : 0.f;
    if (act) {
        unsigned short* zo = zout + (size_t)node * 32 + c0;
        uint4 wa, wb;
        wa.x = pack2(o[0], o[1]);   wa.y = pack2(o[2], o[3]);
        wa.z = pack2(o[4], o[5]);   wa.w = pack2(o[6], o[7]);
        wb.x = pack2(o[8], o[9]);   wb.y = pack2(o[10], o[11]);
        wb.z = pack2(o[12], o[13]); wb.w = pack2(o[14], o[15]);
        *reinterpret_cast<uint4*>(zo) = wa;
        *reinterpret_cast<uint4*>(zo + 8) = wb;
    }
    __syncthreads();   // all zin(y) reads done -> safe to overwrite
    #pragma unroll
    for (int j = 0; j < 16; j++) zin[n][c0 + j] = act ? o[j] : 0.f;
    __syncthreads();
    if (t < 32) {
        float s = 0.f, sq = 0.f;
        for (int nn = 0; nn < 128; nn++) {
            float v = zin[nn][t];
            s += v; sq += v * v;
        }
        atomicAdd(&statsOut[t], s);
        atomicAdd(&statsOut[32 + t], sq);
    }
}

// ====== pool: batch is SORTED -> one block per graph, binary search ======
__global__ __launch_bounds__(256) void pool_seg_k(
        const unsigned short* __restrict__ z,
        const float* __restrict__ statsIn,
        const float* __restrict__ gamma, const float* __restrict__ beta,
        const int* __restrict__ batch, float* __restrict__ g) {
    __shared__ float lsc[64];
    __shared__ float part[32][33];
    int t = threadIdx.x, slot = t >> 3, q = t & 7, c0 = q * 4;
    int gr = blockIdx.x;
    if (t < 32) {
        float mean = statsIn[t] * (1.f / NN);
        float var  = statsIn[32 + t] * (1.f / NN) - mean * mean;
        float scale = gamma[t] * rsqrtf(var + BN_EPS);
        lsc[t] = scale;
        lsc[32 + t] = beta[t] - mean * scale;
    }
    int lo = 0, hi = NN;
    while (lo < hi) { int mid = (lo + hi) >> 1; if (batch[mid] < gr) lo = mid + 1; else hi = mid; }
    int start = lo;
    hi = NN;
    while (lo < hi) { int mid = (lo + hi) >> 1; if (batch[mid] < gr + 1) lo = mid + 1; else hi = mid; }
    int end = lo;
    float a0 = 0.f, a1 = 0.f, a2 = 0.f, a3 = 0.f;
    for (int i = start + slot; i < end; i += 32) {
        ushort4 v = *reinterpret_cast<const ushort4*>(z + (size_t)i * 32 + c0);
        a0 += h2f(v.x); a1 += h2f(v.y); a2 += h2f(v.z); a3 += h2f(v.w);
    }
    part[slot][c0+0] = a0; part[slot][c0+1] = a1;
    part[slot][c0+2] = a2; part[slot][c0+3] = a3;
    __syncthreads();
    if (t < 32) {
        float s = 0.f;
        for (int sl = 0; sl < 32; sl++) s += part[sl][t];
        float cnt = (float)(end - start);
        g[(size_t)gr * 32 + t] = s * lsc[t] + cnt * lsc[32 + t];
    }
}

// ---------------- head: fc1 -> relu -> fc2 -> log_softmax ----------------
__global__ __launch_bounds__(256) void head_k(
        const float* __restrict__ g,
        const float* __restrict__ fc1w, const float* __restrict__ fc1b,
        const float* __restrict__ fc2w, const float* __restrict__ fc2b,
        float* __restrict__ out) {
    __shared__ float lw1[1024], lb1[32], lw2[64], lb2[2];
    int t = threadIdx.x;
    for (int i = t; i < 1024; i += 256) lw1[i] = fc1w[i];
    if (t < 32) lb1[t] = fc1b[t];
    if (t < 64) lw2[t] = fc2w[t];
    if (t < 2) lb2[t] = fc2b[t];
    __syncthreads();
    float gv[32];
    #pragma unroll
    for (int c = 0; c < 32; c++) gv[c] = g[(size_t)t * 32 + c];
    float o0 = lb2[0], o1 = lb2[1];
    #pragma unroll 4
    for (int k = 0; k < 32; k++) {
        float a = lb1[k];
        #pragma unroll
        for (int c = 0; c < 32; c++) a += gv[c] * lw1[c * 32 + k];
        a = a > 0.f ? a : 0.f;
        o0 += a * lw2[k * 2 + 0];
        o1 += a * lw2[k * 2 + 1];
    }
    float m = fmaxf(o0, o1);
    float lse = m + logf(expf(o0 - m) + expf(o1 - m));
    out[t * 2 + 0] = o0 - lse;
    out[t * 2 + 1] = o1 - lse;
}

extern "C" void kernel_launch(void* const* d_in, const int* in_sizes, int n_in,
                              void* d_out, int out_size, void* d_ws, size_t ws_size,
                              hipStream_t stream) {
    const float* x      = (const float*)d_in[0];
    const int*   ei     = (const int*)d_in[1];
    const int*   src    = ei;
    const int*   dst    = ei + NE;
    const int*   batch  = (const int*)d_in[2];
    const float* w1_in  = (const float*)d_in[3];
    const float* b1_in  = (const float*)d_in[4];
    const float* w1_out = (const float*)d_in[5];
    const float* b1_out = (const float*)d_in[6];
    const float* ws_in  = (const float*)d_in[7];
    const float* bs_in  = (const float*)d_in[8];
    const float* ws_out = (const float*)d_in[9];
    const float* bs_out = (const float*)d_in[10];
    const float* gamma  = (const float*)d_in[11];
    const float* beta   = (const float*)d_in[12];
    const float* fc1w   = (const float*)d_in[13];
    const float* fc1b   = (const float*)d_in[14];
    const float* fc2w   = (const float*)d_in[15];
    const float* fc2b   = (const float*)d_in[16];
    float* out = (float*)d_out;

    // ---- workspace layout (16B alignment maintained) ----
    unsigned short* bufA = (unsigned short*)d_ws;        // NN*32 fp16
    unsigned short* bufB = bufA + (size_t)NN * 32;       // NN*32 fp16
    float* stats  = (float*)(bufB + (size_t)NN * 32);    // 5*64 (zeroed)
    int*   bcur   = (int*)(stats + 5 * 64);              // NPART (zeroed, adjacent)
    float* g      = (float*)(bcur + NPART);              // NG*32
    int*   perm   = (int*)(g + (size_t)NG * 32);         // NN
    int*   rowptr = perm + NN;                           // NN+4
    int*   csr    = rowptr + NN + 4;                     // NE
    unsigned int* bpk = (unsigned int*)(csr + NE);       // NPART*CAP

    // ---- zero stats + bucket cursors in one memset ----
    hipMemsetAsync(stats, 0, (size_t)(5 * 64 + NPART) * sizeof(int), stream);

    // ---- CSR build ----
    bucket_k<<<NBLK, 256, 0, stream>>>(src, dst, bcur, bpk);
    build_k<<<NPART, 256, 0, stream>>>(bcur, bpk, rowptr, csr, perm);

    // ---- layer 1 (input dim 2) -> stats[0] ----
    gmlp1_k<<<(NN + 63) / 64, 64, 0, stream>>>(x, perm, rowptr, csr,
                                               w1_in, b1_in, w1_out, b1_out, bufA, stats);

    // ---- layers 2..5 (input dim 32); BN(j) recomputed in-block ----
    const unsigned short* cur = bufA;
    unsigned short* nxt = bufB;
    for (int j = 0; j < 4; j++) {
        gmlp32_k<<<(NN + 127) / 128, 256, 0, stream>>>(cur, perm, stats + j * 64,
                                              gamma + j * 32, beta + j * 32,
                                              rowptr, csr,
                                              ws_in + j * 1024, bs_in + j * 32,
                                              ws_out + j * 1024, bs_out + j * 32,
                                              nxt, stats + (j + 1) * 64);
        unsigned short* tmp = (unsigned short*)cur; cur = nxt; nxt = tmp;
    }

    // ---- pool (BN(4) in-block) + head ----
    pool_seg_k<<<NG, 256, 0, stream>>>(cur, stats + 4 * 64,
                                       gamma + 4 * 32, beta + 4 * 32, batch, g);
    head_k<<<1, 256, 0, stream>>>(g, fc1w, fc1b, fc2w, fc2b, out);
}

// Round 13
// 389.384 us; speedup vs baseline: 1.6114x; 1.0615x over previous
//
#include <hip/hip_runtime.h>
#include <math.h>

#define NN 100000
#define NE 1600000
#define NG 256
#define NPART 200
#define PS 500                        // nodes per partition (9 bits)
#define CAP 9000                      // bucket capacity (mean 8000, +11 sigma)
#define EPB 2048                      // edges per bucket_k block
#define NBLK ((NE + EPB - 1) / EPB)   // 782
#define DEGB 64                       // degree bins for counting sort
static constexpr float BN_EPS = 1e-5f;

// ---- fp16 helpers (HW RNE via v_cvt) ----
__device__ inline float h2f(unsigned short u) {
    _Float16 h; __builtin_memcpy(&h, &u, 2); return (float)h;
}
__device__ inline unsigned short f2h(float f) {
    _Float16 h = (_Float16)f; unsigned short u; __builtin_memcpy(&u, &h, 2); return u;
}
__device__ inline unsigned int pack2(float a, float b) {
    return (unsigned int)f2h(a) | ((unsigned int)f2h(b) << 16);
}

// ======= CSR stage 1: bucket edges by dst partition; packed u32 payload ======
__global__ __launch_bounds__(256) void bucket_k(const int* __restrict__ src,
                                                const int* __restrict__ dst,
                                                int* __restrict__ bcur,
                                                unsigned int* __restrict__ bpk) {
    __shared__ int cnt[NPART];
    __shared__ int base[NPART];
    int t = threadIdx.x;
    for (int i = t; i < NPART; i += 256) cnt[i] = 0;
    __syncthreads();
    int eb = blockIdx.x * EPB + t * 8;   // all-or-nothing (tail is 64x8)
    bool act = eb < NE;
    int myp[8], myr[8];
    unsigned int pk[8];
    if (act) {
        int4 d0 = *reinterpret_cast<const int4*>(dst + eb);
        int4 d1 = *reinterpret_cast<const int4*>(dst + eb + 4);
        int4 s0 = *reinterpret_cast<const int4*>(src + eb);
        int4 s1 = *reinterpret_cast<const int4*>(src + eb + 4);
        int dd[8] = {d0.x,d0.y,d0.z,d0.w,d1.x,d1.y,d1.z,d1.w};
        int ss[8] = {s0.x,s0.y,s0.z,s0.w,s1.x,s1.y,s1.z,s1.w};
        #pragma unroll
        for (int i = 0; i < 8; i++) {
            int p = dd[i] / PS;
            myp[i] = p;
            pk[i] = ((unsigned int)ss[i] << 9) | (unsigned int)(dd[i] - p * PS);
            myr[i] = atomicAdd(&cnt[p], 1);
        }
    }
    __syncthreads();
    for (int i = t; i < NPART; i += 256)
        base[i] = cnt[i] ? atomicAdd(&bcur[i], cnt[i]) : 0;
    __syncthreads();
    if (act) {
        #pragma unroll
        for (int i = 0; i < 8; i++)
            bpk[myp[i] * CAP + base[myp[i]] + myr[i]] = pk[i];
    }
}

// ==== CSR stage 2: per-partition hist + scan + deg-sort perm + place =========
__global__ __launch_bounds__(256) void build_k(const int* __restrict__ bcur,
                                               const unsigned int* __restrict__ bpk,
                                               int* __restrict__ rowptr,
                                               int* __restrict__ csr,
                                               int* __restrict__ perm) {
    __shared__ int hist[PS];          // histogram -> cursor
    __shared__ int allc[NPART];
    __shared__ int psum[256];
    __shared__ int bc[DEGB];
    int p = blockIdx.x, t = threadIdx.x;
    int lo = p * PS;
    if (t < NPART) allc[t] = bcur[t];
    for (int i = t; i < PS; i += 256) hist[i] = 0;
    if (t < DEGB) bc[t] = 0;
    __syncthreads();
    int base = 0;
    for (int q = 0; q < p; q++) base += allc[q];
    int cnt = allc[p];
    const unsigned int* bp = bpk + p * CAP;
    const uint4* bp4 = reinterpret_cast<const uint4*>(bp);
    int n4 = cnt >> 2;
    for (int i = t; i < n4; i += 256) {
        uint4 v = bp4[i];
        atomicAdd(&hist[v.x & 511u], 1);
        atomicAdd(&hist[v.y & 511u], 1);
        atomicAdd(&hist[v.z & 511u], 1);
        atomicAdd(&hist[v.w & 511u], 1);
    }
    for (int i = 4 * n4 + t; i < cnt; i += 256) atomicAdd(&hist[bp[i] & 511u], 1);
    __syncthreads();
    int j0 = t * 2;
    int d0v = 0, d1v = 0, tsum = 0;
    if (j0 < PS) {
        d0v = hist[j0]; d1v = hist[j0 + 1];
        tsum = d0v + d1v;
        atomicAdd(&bc[d0v < DEGB ? d0v : DEGB - 1], 1);
        atomicAdd(&bc[d1v < DEGB ? d1v : DEGB - 1], 1);
    }
    psum[t] = tsum;
    __syncthreads();
    for (int off = 1; off < 256; off <<= 1) {
        int v = (t >= off) ? psum[t - off] : 0;
        __syncthreads();
        psum[t] += v;
        __syncthreads();
    }
    int texcl = psum[t] - tsum;
    if (j0 < PS) {
        int run = base + texcl;
        hist[j0] = run; rowptr[lo + j0] = run; run += d0v;
        hist[j0 + 1] = run; rowptr[lo + j0 + 1] = run; run += d1v;
    }
    if (p == NPART - 1 && t == 0) rowptr[NN] = base + cnt;
    __syncthreads();
    if (t == 0) {
        int run = 0;
        #pragma unroll
        for (int b = 0; b < DEGB; b++) { int c = bc[b]; bc[b] = run; run += c; }
    }
    __syncthreads();
    if (j0 < PS) {
        int r0 = atomicAdd(&bc[d0v < DEGB ? d0v : DEGB - 1], 1);
        perm[lo + r0] = lo + j0;
        int r1 = atomicAdd(&bc[d1v < DEGB ? d1v : DEGB - 1], 1);
        perm[lo + r1] = lo + j0 + 1;
    }
    __syncthreads();
    for (int i = t; i < n4; i += 256) {
        uint4 v = bp4[i];
        csr[atomicAdd(&hist[v.x & 511u], 1)] = v.x >> 9;
        csr[atomicAdd(&hist[v.y & 511u], 1)] = v.y >> 9;
        csr[atomicAdd(&hist[v.z & 511u], 1)] = v.z >> 9;
        csr[atomicAdd(&hist[v.w & 511u], 1)] = v.w >> 9;
    }
    for (int i = 4 * n4 + t; i < cnt; i += 256)
        csr[atomicAdd(&hist[bp[i] & 511u], 1)] = bp[i] >> 9;
}

// ====== layer 1 v2: 2 lanes/node, 128 nodes/block, shfl-combined gather ======
__global__ __launch_bounds__(256) void gmlp1_k(
        const float* __restrict__ x, const int* __restrict__ perm,
        const int* __restrict__ rowptr, const int* __restrict__ csr,
        const float* __restrict__ w_in, const float* __restrict__ b_in,
        const float* __restrict__ w_out, const float* __restrict__ b_out,
        unsigned short* __restrict__ zout, float* __restrict__ stats) {
    __shared__ float lwi[64], lbi[32], lwo[1024], lbo[32];
    __shared__ float zin[128][33];
    int t = threadIdx.x;
    int n = t >> 1, q = t & 1, c0 = q * 16;
    for (int i = t; i < 1024; i += 256) lwo[i] = w_out[i];
    if (t < 64) lwi[t] = w_in[t];
    if (t < 32) { lbi[t] = b_in[t]; lbo[t] = b_out[t]; }
    __syncthreads();
    int gid = blockIdx.x * 128 + n;
    bool act = gid < NN;
    int node = act ? perm[gid] : 0;
    float h0 = 0.f, h1 = 0.f;
    if (act) {
        int rs = rowptr[node], re = rowptr[node + 1];
        if (q == 0) {
            float2 self = *reinterpret_cast<const float2*>(x + 2 * (size_t)node);
            h0 = self.x; h1 = self.y;
        }
        float g0 = 0.f, g1 = 0.f;
        int k = rs + q;           // lane q takes every other neighbor
        for (; k + 6 < re; k += 8) {
            int s0 = csr[k], s1 = csr[k + 2], s2 = csr[k + 4], s3 = csr[k + 6];
            float2 v0 = *reinterpret_cast<const float2*>(x + 2 * (size_t)s0);
            float2 v1 = *reinterpret_cast<const float2*>(x + 2 * (size_t)s1);
            float2 v2 = *reinterpret_cast<const float2*>(x + 2 * (size_t)s2);
            float2 v3 = *reinterpret_cast<const float2*>(x + 2 * (size_t)s3);
            h0 += v0.x + v2.x; h1 += v0.y + v2.y;
            g0 += v1.x + v3.x; g1 += v1.y + v3.y;
        }
        for (; k < re; k += 2) {
            int s = csr[k];
            float2 v = *reinterpret_cast<const float2*>(x + 2 * (size_t)s);
            h0 += v.x; h1 += v.y;
        }
        h0 += g0; h1 += g1;
    }
    // combine lane pair (t and t^1 are the same node)
    h0 += __shfl_xor(h0, 1);
    h1 += __shfl_xor(h1, 1);
    // GEMM1 (input dim 2): lane computes 16 channels of y
    float y[16];
    #pragma unroll
    for (int j = 0; j < 16; j++) {
        float a = lbi[c0 + j] + h0 * lwi[c0 + j] + h1 * lwi[32 + c0 + j];
        y[j] = a > 0.f ? a : 0.f;
    }
    #pragma unroll
    for (int j = 0; j < 16; j++) zin[n][c0 + j] = act ? y[j] : 0.f;
    __syncthreads();
    // GEMM2: z = relu(y @ w_out + b_out); lane computes 16 channels
    float o[16];
    #pragma unroll
    for (int j = 0; j < 16; j++) o[j] = lbo[c0 + j];
    #pragma unroll
    for (int c = 0; c < 32; c++) {
        float yv = zin[n][c];
        #pragma unroll
        for (int j = 0; j < 16; j++) o[j] += yv * lwo[c * 32 + c0 + j];
    }
    #pragma unroll
    for (int j = 0; j < 16; j++) o[j] = o[j] > 0.f ? o[j] : 0.f;
    if (act) {
        unsigned short* zo = zout + (size_t)node * 32 + c0;
        uint4 wa, wb;
        wa.x = pack2(o[0], o[1]);   wa.y = pack2(o[2], o[3]);
        wa.z = pack2(o[4], o[5]);   wa.w = pack2(o[6], o[7]);
        wb.x = pack2(o[8], o[9]);   wb.y = pack2(o[10], o[11]);
        wb.z = pack2(o[12], o[13]); wb.w = pack2(o[14], o[15]);
        *reinterpret_cast<uint4*>(zo) = wa;
        *reinterpret_cast<uint4*>(zo + 8) = wb;
    }
    __syncthreads();   // all zin(y) reads done -> safe to overwrite
    #pragma unroll
    for (int j = 0; j < 16; j++) zin[n][c0 + j] = act ? o[j] : 0.f;
    __syncthreads();
    if (t < 32) {
        float s = 0.f, sq = 0.f;
        for (int nn = 0; nn < 128; nn++) {
            float v = zin[nn][t];
            s += v; sq += v * v;
        }
        atomicAdd(&stats[t], s);
        atomicAdd(&stats[32 + t], sq);
    }
}

// ======= heavy layer v3: 2 lanes/node, 128 nodes/block, 4-row unroll ========
__global__ __launch_bounds__(256) void gmlp32_k(
        const unsigned short* __restrict__ z, const int* __restrict__ perm,
        const float* __restrict__ statsIn,
        const float* __restrict__ gamma, const float* __restrict__ beta,
        const int* __restrict__ rowptr, const int* __restrict__ csr,
        const float* __restrict__ w_in, const float* __restrict__ b_in,
        const float* __restrict__ w_out, const float* __restrict__ b_out,
        unsigned short* __restrict__ zout, float* __restrict__ statsOut) {
    __shared__ float lwi[1024], lwo[1024], lbi[32], lbo[32], lsc[64];
    __shared__ float zin[128][33];
    int t = threadIdx.x;
    int n = t >> 1, q = t & 1, c0 = q * 16;
    for (int i = t; i < 1024; i += 256) { lwi[i] = w_in[i]; lwo[i] = w_out[i]; }
    if (t < 32) {
        lbi[t] = b_in[t]; lbo[t] = b_out[t];
        float mean = statsIn[t] * (1.f / NN);
        float var  = statsIn[32 + t] * (1.f / NN) - mean * mean;
        float scale = gamma[t] * rsqrtf(var + BN_EPS);
        lsc[t] = scale;
        lsc[32 + t] = beta[t] - mean * scale;
    }
    __syncthreads();
    int gid = blockIdx.x * 128 + n;
    bool act = gid < NN;
    int node = act ? perm[gid] : 0;
    float a[16];
    #pragma unroll
    for (int j = 0; j < 16; j++) a[j] = 0.f;
    float cntf = 0.f;
    if (act) {
        int rs = rowptr[node], re = rowptr[node + 1];
        cntf = (float)(re - rs + 1);
        const unsigned short* zb = z + (size_t)node * 32 + c0;
        uint4 sa = *reinterpret_cast<const uint4*>(zb);
        uint4 sb = *reinterpret_cast<const uint4*>(zb + 8);
        const unsigned short* pa = reinterpret_cast<const unsigned short*>(&sa);
        const unsigned short* pb = reinterpret_cast<const unsigned short*>(&sb);
        #pragma unroll
        for (int j = 0; j < 8; j++) { a[j] = h2f(pa[j]); a[8 + j] = h2f(pb[j]); }
        int k = rs;
        for (; k + 4 <= re; k += 4) {
            int s0 = csr[k], s1 = csr[k + 1], s2 = csr[k + 2], s3 = csr[k + 3];
            const unsigned short* r0 = z + (size_t)s0 * 32 + c0;
            const unsigned short* r1 = z + (size_t)s1 * 32 + c0;
            const unsigned short* r2 = z + (size_t)s2 * 32 + c0;
            const unsigned short* r3 = z + (size_t)s3 * 32 + c0;
            uint4 v0a = *reinterpret_cast<const uint4*>(r0);
            uint4 v0b = *reinterpret_cast<const uint4*>(r0 + 8);
            uint4 v1a = *reinterpret_cast<const uint4*>(r1);
            uint4 v1b = *reinterpret_cast<const uint4*>(r1 + 8);
            uint4 v2a = *reinterpret_cast<const uint4*>(r2);
            uint4 v2b = *reinterpret_cast<const uint4*>(r2 + 8);
            uint4 v3a = *reinterpret_cast<const uint4*>(r3);
            uint4 v3b = *reinterpret_cast<const uint4*>(r3 + 8);
            const unsigned short* q0a = reinterpret_cast<const unsigned short*>(&v0a);
            const unsigned short* q0b = reinterpret_cast<const unsigned short*>(&v0b);
            const unsigned short* q1a = reinterpret_cast<const unsigned short*>(&v1a);
            const unsigned short* q1b = reinterpret_cast<const unsigned short*>(&v1b);
            const unsigned short* q2a = reinterpret_cast<const unsigned short*>(&v2a);
            const unsigned short* q2b = reinterpret_cast<const unsigned short*>(&v2b);
            const unsigned short* q3a = reinterpret_cast<const unsigned short*>(&v3a);
            const unsigned short* q3b = reinterpret_cast<const unsigned short*>(&v3b);
            #pragma unroll
            for (int j = 0; j < 8; j++) {
                a[j]     += (h2f(q0a[j]) + h2f(q1a[j])) + (h2f(q2a[j]) + h2f(q3a[j]));
                a[8 + j] += (h2f(q0b[j]) + h2f(q1b[j])) + (h2f(q2b[j]) + h2f(q3b[j]));
            }
        }
        for (; k < re; k++) {
            int s = csr[k];
            const unsigned short* r = z + (size_t)s * 32 + c0;
            uint4 va = *reinterpret_cast<const uint4*>(r);
            uint4 vb = *reinterpret_cast<const uint4*>(r + 8);
            const unsigned short* qa = reinterpret_cast<const unsigned short*>(&va);
            const unsigned short* qb = reinterpret_cast<const unsigned short*>(&vb);
            #pragma unroll
            for (int j = 0; j < 8; j++) { a[j] += h2f(qa[j]); a[8 + j] += h2f(qb[j]); }
        }
    }
    #pragma unroll
    for (int j = 0; j < 16; j++)
        zin[n][c0 + j] = act ? (a[j] * lsc[c0 + j] + cntf * lsc[32 + c0 + j]) : 0.f;
    __syncthreads();
    float y[16];
    #pragma unroll
    for (int j = 0; j < 16; j++) y[j] = lbi[c0 + j];
    #pragma unroll
    for (int c = 0; c < 32; c++) {
        float zv = zin[n][c];
        #pragma unroll
        for (int j = 0; j < 16; j++) y[j] += zv * lwi[c * 32 + c0 + j];
    }
    #pragma unroll
    for (int j = 0; j < 16; j++) y[j] = y[j] > 0.f ? y[j] : 0.f;
    __syncthreads();
    #pragma unroll
    for (int j = 0; j < 16; j++) zin[n][c0 + j] = y[j];
    __syncthreads();
    float o[16];
    #pragma unroll
    for (int j = 0; j < 16; j++) o[j] = lbo[c0 + j];
    #pragma unroll
    for (int c = 0; c < 32; c++) {
        float yv = zin[n][c];
        #pragma unroll
        for (int j = 0; j < 16; j++) o[j] += yv * lwo[c * 32 + c0 + j];
    }
    #pragma unroll
    for (int j = 0; j < 16; j++) o[j] = o[j] > 0.f ? o[j] : 0.f;
    if (act) {
        unsigned short* zo = zout + (size_t)node * 32 + c0;
        uint4 wa, wb;
        wa.x = pack2(o[0], o[1]);   wa.y = pack2(o[2], o[3]);
        wa.z = pack2(o[4], o[5]);   wa.w = pack2(o[6], o[7]);
        wb.x = pack2(o[8], o[9]);   wb.y = pack2(o[10], o[11]);
        wb.z = pack2(o[12], o[13]); wb.w = pack2(o[14], o[15]);
        *reinterpret_cast<uint4*>(zo) = wa;
        *reinterpret_cast<uint4*>(zo + 8) = wb;
    }
    __syncthreads();
    #pragma unroll
    for (int j = 0; j < 16; j++) zin[n][c0 + j] = act ? o[j] : 0.f;
    __syncthreads();
    if (t < 32) {
        float s = 0.f, sq = 0.f;
        for (int nn = 0; nn < 128; nn++) {
            float v = zin[nn][t];
            s += v; sq += v * v;
        }
        atomicAdd(&statsOut[t], s);
        atomicAdd(&statsOut[32 + t], sq);
    }
}

// ====== pool: batch is SORTED -> one block per graph, binary search ======
__global__ __launch_bounds__(256) void pool_seg_k(
        const unsigned short* __restrict__ z,
        const float* __restrict__ statsIn,
        const float* __restrict__ gamma, const float* __restrict__ beta,
        const int* __restrict__ batch, float* __restrict__ g) {
    __shared__ float lsc[64];
    __shared__ float part[32][33];
    int t = threadIdx.x, slot = t >> 3, q = t & 7, c0 = q * 4;
    int gr = blockIdx.x;
    if (t < 32) {
        float mean = statsIn[t] * (1.f / NN);
        float var  = statsIn[32 + t] * (1.f / NN) - mean * mean;
        float scale = gamma[t] * rsqrtf(var + BN_EPS);
        lsc[t] = scale;
        lsc[32 + t] = beta[t] - mean * scale;
    }
    int lo = 0, hi = NN;
    while (lo < hi) { int mid = (lo + hi) >> 1; if (batch[mid] < gr) lo = mid + 1; else hi = mid; }
    int start = lo;
    hi = NN;
    while (lo < hi) { int mid = (lo + hi) >> 1; if (batch[mid] < gr + 1) lo = mid + 1; else hi = mid; }
    int end = lo;
    float a0 = 0.f, a1 = 0.f, a2 = 0.f, a3 = 0.f;
    for (int i = start + slot; i < end; i += 32) {
        ushort4 v = *reinterpret_cast<const ushort4*>(z + (size_t)i * 32 + c0);
        a0 += h2f(v.x); a1 += h2f(v.y); a2 += h2f(v.z); a3 += h2f(v.w);
    }
    part[slot][c0+0] = a0; part[slot][c0+1] = a1;
    part[slot][c0+2] = a2; part[slot][c0+3] = a3;
    __syncthreads();
    if (t < 32) {
        float s = 0.f;
        for (int sl = 0; sl < 32; sl++) s += part[sl][t];
        float cnt = (float)(end - start);
        g[(size_t)gr * 32 + t] = s * lsc[t] + cnt * lsc[32 + t];
    }
}

// ---------------- head: fc1 -> relu -> fc2 -> log_softmax ----------------
__global__ __launch_bounds__(256) void head_k(
        const float* __restrict__ g,
        const float* __restrict__ fc1w, const float* __restrict__ fc1b,
        const float* __restrict__ fc2w, const float* __restrict__ fc2b,
        float* __restrict__ out) {
    __shared__ float lw1[1024], lb1[32], lw2[64], lb2[2];
    int t = threadIdx.x;
    for (int i = t; i < 1024; i += 256) lw1[i] = fc1w[i];
    if (t < 32) lb1[t] = fc1b[t];
    if (t < 64) lw2[t] = fc2w[t];
    if (t < 2) lb2[t] = fc2b[t];
    __syncthreads();
    float gv[32];
    #pragma unroll
    for (int c = 0; c < 32; c++) gv[c] = g[(size_t)t * 32 + c];
    float o0 = lb2[0], o1 = lb2[1];
    #pragma unroll 4
    for (int k = 0; k < 32; k++) {
        float a = lb1[k];
        #pragma unroll
        for (int c = 0; c < 32; c++) a += gv[c] * lw1[c * 32 + k];
        a = a > 0.f ? a : 0.f;
        o0 += a * lw2[k * 2 + 0];
        o1 += a * lw2[k * 2 + 1];
    }
    float m = fmaxf(o0, o1);
    float lse = m + logf(expf(o0 - m) + expf(o1 - m));
    out[t * 2 + 0] = o0 - lse;
    out[t * 2 + 1] = o1 - lse;
}

extern "C" void kernel_launch(void* const* d_in, const int* in_sizes, int n_in,
                              void* d_out, int out_size, void* d_ws, size_t ws_size,
                              hipStream_t stream) {
    const float* x      = (const float*)d_in[0];
    const int*   ei     = (const int*)d_in[1];
    const int*   src    = ei;
    const int*   dst    = ei + NE;
    const int*   batch  = (const int*)d_in[2];
    const float* w1_in  = (const float*)d_in[3];
    const float* b1_in  = (const float*)d_in[4];
    const float* w1_out = (const float*)d_in[5];
    const float* b1_out = (const float*)d_in[6];
    const float* ws_in  = (const float*)d_in[7];
    const float* bs_in  = (const float*)d_in[8];
    const float* ws_out = (const float*)d_in[9];
    const float* bs_out = (const float*)d_in[10];
    const float* gamma  = (const float*)d_in[11];
    const float* beta   = (const float*)d_in[12];
    const float* fc1w   = (const float*)d_in[13];
    const float* fc1b   = (const float*)d_in[14];
    const float* fc2w   = (const float*)d_in[15];
    const float* fc2b   = (const float*)d_in[16];
    float* out = (float*)d_out;

    // ---- workspace layout (16B alignment maintained) ----
    unsigned short* bufA = (unsigned short*)d_ws;        // NN*32 fp16
    unsigned short* bufB = bufA + (size_t)NN * 32;       // NN*32 fp16
    float* stats  = (float*)(bufB + (size_t)NN * 32);    // 5*64 (zeroed)
    int*   bcur   = (int*)(stats + 5 * 64);              // NPART (zeroed, adjacent)
    float* g      = (float*)(bcur + NPART);              // NG*32
    int*   perm   = (int*)(g + (size_t)NG * 32);         // NN
    int*   rowptr = perm + NN;                           // NN+4
    int*   csr    = rowptr + NN + 4;                     // NE
    unsigned int* bpk = (unsigned int*)(csr + NE);       // NPART*CAP

    // ---- zero stats + bucket cursors in one memset ----
    hipMemsetAsync(stats, 0, (size_t)(5 * 64 + NPART) * sizeof(int), stream);

    // ---- CSR build ----
    bucket_k<<<NBLK, 256, 0, stream>>>(src, dst, bcur, bpk);
    build_k<<<NPART, 256, 0, stream>>>(bcur, bpk, rowptr, csr, perm);

    // ---- layer 1 (input dim 2) -> stats[0] ----
    gmlp1_k<<<(NN + 127) / 128, 256, 0, stream>>>(x, perm, rowptr, csr,
                                                  w1_in, b1_in, w1_out, b1_out, bufA, stats);

    // ---- layers 2..5 (input dim 32); BN(j) recomputed in-block ----
    const unsigned short* cur = bufA;
    unsigned short* nxt = bufB;
    for (int j = 0; j < 4; j++) {
        gmlp32_k<<<(NN + 127) / 128, 256, 0, stream>>>(cur, perm, stats + j * 64,
                                              gamma + j * 32, beta + j * 32,
                                              rowptr, csr,
                                              ws_in + j * 1024, bs_in + j * 32,
                                              ws_out + j * 1024, bs_out + j * 32,
                                              nxt, stats + (j + 1) * 64);
        unsigned short* tmp = (unsigned short*)cur; cur = nxt; nxt = tmp;
    }

    // ---- pool (BN(4) in-block) + head ----
    pool_seg_k<<<NG, 256, 0, stream>>>(cur, stats + 4 * 64,
                                       gamma + 4 * 32, beta + 4 * 32, batch, g);
    head_k<<<1, 256, 0, stream>>>(g, fc1w, fc1b, fc2w, fc2b, out);
}